// Round 2
// baseline (1374.639 us; speedup 1.0000x reference)
//
#include <hip/hip_runtime.h>

#define KK 30
#define F 148
#define NNODE 16384
#define NPB 16   // nodes per prep_node block

typedef short bf16x8 __attribute__((ext_vector_type(8)));
typedef float f32x4v __attribute__((ext_vector_type(4)));

// ---- bf16 helpers (RNE) ----
__device__ __forceinline__ ushort f2bf(float x) {
  unsigned u = __float_as_uint(x);
  unsigned r = (u + 0x7FFF + ((u >> 16) & 1)) >> 16;
  return (ushort)r;
}
__device__ __forceinline__ float bf2f(ushort b) { return __uint_as_float(((unsigned)b) << 16); }
__device__ __forceinline__ unsigned pk2(float x, float y) {
  return (unsigned)f2bf(x) | ((unsigned)f2bf(y) << 16);
}
__device__ __forceinline__ void bsplit(float x, ushort& h, ushort& l) {
  ushort hh = f2bf(x); h = hh; l = f2bf(x - bf2f(hh));
}

// d_ws layout: [ s1bg 16384*100 fl ][ vhbg 16384*96 fl ][ wsb ushorts ]
#define WS_S1B 0
#define WS_VHB (NNODE * 100)
#define WS_WSB (NNODE * 100 + NNODE * 96)
// wsb (ushort offsets): pre-transposed split weights Bt[n][k], hi+lo
#define B1HI 0
#define B1LO 17920   // 112*160
#define B2HI 35840
#define B2LO 50176   // 112*128
#define B3HI 64512
#define B3LO 78848

__global__ void prep_weights(const float* __restrict__ Ws1, const float* __restrict__ Ws2,
                             const float* __restrict__ Ws3, ushort* __restrict__ ws) {
  int i = blockIdx.x * 256 + threadIdx.x;
  if (i < 17920) {                       // B1: [112][160], src rows 100..231 of Ws1 [232][100]
    int n = i / 160, k = i % 160;
    float w = (n < 100 && k < 132) ? Ws1[(100 + k) * 100 + n] : 0.f;
    ushort h, l; bsplit(w, h, l);
    ws[B1HI + i] = h; ws[B1LO + i] = l;
  } else if (i < 17920 + 14336) {        // B2: [112][128], src Ws2 [116][100]
    int j = i - 17920; int n = j / 128, k = j % 128;
    float w = (n < 100 && k < 116) ? Ws2[k * 100 + n] : 0.f;
    ushort h, l; bsplit(w, h, l);
    ws[B2HI + j] = h; ws[B2LO + j] = l;
  } else if (i < 17920 + 2 * 14336) {    // B3: [112][128], src Ws3 [116][100]
    int j = i - 17920 - 14336; int n = j / 128, k = j % 128;
    float w = (n < 100 && k < 116) ? Ws3[k * 100 + n] : 0.f;
    ushort h, l; bsplit(w, h, l);
    ws[B3HI + j] = h; ws[B3LO + j] = l;
  }
}

// per-node k-independent precompute, 16 nodes per block with Ws1^T staged in LDS.
// (R1 version re-read 40KB of Ws1 from L2 per node-block; this amortizes it 16x
//  and keeps all 256 threads busy on flattened tasks.)
__global__ __launch_bounds__(256)
void prep_node(const float* __restrict__ h_V, const float* __restrict__ Ws1,
               const float* __restrict__ bs1, const float* __restrict__ Wh1,
               float* __restrict__ s1bg, float* __restrict__ vhbg) {
  __shared__ float wt[100 * 101];   // Ws1^T [n][i], pad 101 -> conflict-free column reads
  __shared__ float wh[512];         // Wh1 [16][32]
  __shared__ float svs[NPB * 148];
  const int tid = threadIdx.x;
  const long node0 = (long)blockIdx.x * NPB;
  for (int idx = tid; idx < 10000; idx += 256) {
    int i = idx / 100, n = idx - i * 100;
    wt[n * 101 + i] = Ws1[idx];     // coalesced read, scattered LDS write
  }
  for (int idx = tid; idx < 512; idx += 256) wh[idx] = Wh1[idx];
  for (int idx = tid; idx < NPB * 148; idx += 256) {
    int nd = idx / 148, f = idx - nd * 148;
    svs[idx] = h_V[(node0 + nd) * 148 + f];
  }
  __syncthreads();
  for (int task = tid; task < NPB * 100; task += 256) {
    int nd = task / 100, n = task - nd * 100;
    const float* s = svs + nd * 148 + 48;
    const float* w = wt + n * 101;
    float acc = bs1[n];
#pragma unroll 10
    for (int i = 0; i < 100; i++) acc = fmaf(s[i], w[i], acc);
    s1bg[(node0 + nd) * 100 + n] = acc;
  }
  for (int task = tid; task < NPB * 32; task += 256) {
    int nd = task >> 5, h = task & 31;
    const float* s = svs + nd * 148;
    float a0 = 0.f, a1 = 0.f, a2 = 0.f;
#pragma unroll 4
    for (int i = 0; i < 16; i++) {
      float w = wh[i * 32 + h];
      a0 = fmaf(s[3*i], w, a0); a1 = fmaf(s[3*i+1], w, a1); a2 = fmaf(s[3*i+2], w, a2);
    }
    vhbg[(node0 + nd) * 96 + 3*h + 0] = a0;
    vhbg[(node0 + nd) * 96 + 3*h + 1] = a1;
    vhbg[(node0 + nd) * 96 + 3*h + 2] = a2;
  }
}

#define DECL12 float a00=0,a01=0,a02=0,a10=0,a11=0,a12=0,a20=0,a21=0,a22=0,a30=0,a31=0,a32=0;
#define FMA3x4(v0_,v1_,v2_,w_) \
  a00=fmaf(v0_,w_.x,a00); a01=fmaf(v1_,w_.x,a01); a02=fmaf(v2_,w_.x,a02); \
  a10=fmaf(v0_,w_.y,a10); a11=fmaf(v1_,w_.y,a11); a12=fmaf(v2_,w_.y,a12); \
  a20=fmaf(v0_,w_.z,a20); a21=fmaf(v1_,w_.z,a21); a22=fmaf(v2_,w_.z,a22); \
  a30=fmaf(v0_,w_.w,a30); a31=fmaf(v1_,w_.w,a31); a32=fmaf(v2_,w_.w,a32);

#define GATE3(x0,x1,x2,d0,d1,d2) { float vn_=sqrtf((x0)*(x0)+(x1)*(x1)+(x2)*(x2)+1e-8f); \
  float g_=1.f/(1.f+expf(-vn_)); d0=(x0)*g_; d1=(x1)*g_; d2=(x2)*g_; }

// vector-path matvec, 4 outputs, bf16-packed source (VBu), fp32 dest
template<int NI, bool GATEF>
__device__ __forceinline__ void vtaskb(const unsigned* __restrict__ vsrc,
                                       const float* __restrict__ wbase, int wstride,
                                       float* __restrict__ vdst)
{
  DECL12
#pragma unroll 4
  for (int h2 = 0; h2 < NI / 2; h2++) {
    unsigned d0 = vsrc[3*h2+0], d1 = vsrc[3*h2+1], d2 = vsrc[3*h2+2];
    float4 w0 = *(const float4*)(wbase + (2*h2) * wstride);
    float4 w1 = *(const float4*)(wbase + (2*h2+1) * wstride);
    float e0 = bf2f((ushort)d0), e1 = bf2f((ushort)(d0 >> 16)), e2 = bf2f((ushort)d1);
    float g0 = bf2f((ushort)(d1 >> 16)), g1 = bf2f((ushort)d2), g2 = bf2f((ushort)(d2 >> 16));
    FMA3x4(e0, e1, e2, w0)
    FMA3x4(g0, g1, g2, w1)
  }
  if (GATEF) {
    GATE3(a00,a01,a02, vdst[0],vdst[1],vdst[2])
    GATE3(a10,a11,a12, vdst[3],vdst[4],vdst[5])
    GATE3(a20,a21,a22, vdst[6],vdst[7],vdst[8])
    GATE3(a30,a31,a32, vdst[9],vdst[10],vdst[11])
  } else {
    vdst[0]=a00; vdst[1]=a01; vdst[2]=a02;  vdst[3]=a10; vdst[4]=a11; vdst[5]=a12;
    vdst[6]=a20; vdst[7]=a21; vdst[8]=a22;  vdst[9]=a30; vdst[10]=a31; vdst[11]=a32;
  }
}

// Fused: gated v-task (NI inputs -> 16 outputs, this thread owns o0=c*4..c*4+3)
// + next-stage vh (16 -> 16) via 4-lane xor exchange of the gated values.
// Writes vh (bf16) into the VBu row + packed norms into the A-tile norm column.
// No __restrict__ on vrow_u: it aliases vsrc (read-before-write is enforced by
// the data dependency: every written value depends on all reads of the row).
template<int NI>
__device__ __forceinline__ void v_vh_fused(const unsigned* vsrc,
                                           const float* __restrict__ Wv,   // pre-offset by o0
                                           const float* __restrict__ Whn,  // [16][16]
                                           int c, int h0,
                                           unsigned* vrow_u, ushort* ncol)
{
  DECL12
#pragma unroll
  for (int h2 = 0; h2 < NI / 2; h2++) {
    unsigned d0 = vsrc[3*h2+0], d1 = vsrc[3*h2+1], d2 = vsrc[3*h2+2];
    float4 w0 = *(const float4*)(Wv + (2*h2) * 16);
    float4 w1 = *(const float4*)(Wv + (2*h2+1) * 16);
    float e0 = bf2f((ushort)d0), e1 = bf2f((ushort)(d0 >> 16)), e2 = bf2f((ushort)d1);
    float f0 = bf2f((ushort)(d1 >> 16)), f1 = bf2f((ushort)d2), f2 = bf2f((ushort)(d2 >> 16));
    FMA3x4(e0, e1, e2, w0)
    FMA3x4(f0, f1, f2, w1)
  }
  float gg[12];
  GATE3(a00,a01,a02, gg[0],gg[1],gg[2])
  GATE3(a10,a11,a12, gg[3],gg[4],gg[5])
  GATE3(a20,a21,a22, gg[6],gg[7],gg[8])
  GATE3(a30,a31,a32, gg[9],gg[10],gg[11])
  a00=0;a01=0;a02=0;a10=0;a11=0;a12=0;a20=0;a21=0;a22=0;a30=0;a31=0;a32=0;
#pragma unroll
  for (int m = 0; m < 4; m++) {
    float t[12];
#pragma unroll
    for (int z = 0; z < 12; z++) t[z] = (m == 0) ? gg[z] : __shfl_xor(gg[z], m);
    int ob = (c ^ m) * 4;    // 4 v-outputs held by partner lane
#pragma unroll
    for (int j = 0; j < 4; j++) {
      float4 w = *(const float4*)(Whn + (ob + j) * 16 + h0);
      FMA3x4(t[3*j], t[3*j+1], t[3*j+2], w)
    }
  }
  unsigned* vb = vrow_u + ((3 * h0) >> 1);
  vb[0]=pk2(a00,a01); vb[1]=pk2(a02,a10); vb[2]=pk2(a11,a12);
  vb[3]=pk2(a20,a21); vb[4]=pk2(a22,a30); vb[5]=pk2(a31,a32);
  float n0 = sqrtf(a00*a00+a01*a01+a02*a02 + 1e-8f);
  float n1 = sqrtf(a10*a10+a11*a11+a12*a12 + 1e-8f);
  float n2 = sqrtf(a20*a20+a21*a21+a22*a22 + 1e-8f);
  float n3 = sqrtf(a30*a30+a31*a31+a32*a32 + 1e-8f);
  unsigned* p = (unsigned*)ncol;
  p[0] = pk2(n0, n1); p[1] = pk2(n2, n3);
}

// 2-term split-bf16 MFMA over one n-tile, two m-tiles. A hi-only from LDS; B hi+lo from L2.
template<int NKS>
__device__ __forceinline__ void mfma_nt2(const ushort* __restrict__ A, int astr,
                                         const ushort* __restrict__ B_hi,
                                         const ushort* __restrict__ B_lo,
                                         int lane, f32x4v& c0, f32x4v& c1)
{
  int r = lane & 15, q = lane >> 4;
  const int ka = q * 8;
#pragma unroll
  for (int ks = 0; ks < NKS; ks++) {
    int ko = ka + ks * 32;
    bf16x8 a0 = *(const bf16x8*)(A + r * astr + ko);
    bf16x8 a1 = *(const bf16x8*)(A + (16 + r) * astr + ko);
    bf16x8 bh = *(const bf16x8*)(B_hi + ko);
    bf16x8 bl = *(const bf16x8*)(B_lo + ko);
    c0 = __builtin_amdgcn_mfma_f32_16x16x32_bf16(a0, bh, c0, 0, 0, 0);
    c0 = __builtin_amdgcn_mfma_f32_16x16x32_bf16(a0, bl, c0, 0, 0, 0);
    c1 = __builtin_amdgcn_mfma_f32_16x16x32_bf16(a1, bh, c1, 0, 0, 0);
    c1 = __builtin_amdgcn_mfma_f32_16x16x32_bf16(a1, bl, c1, 0, 0, 0);
  }
}

// LDS pool carving (float offsets), 30888 B -> 5 blocks/CU.
// A1 stride back to 168 ushorts (336B: 2-way bank alias = free; 160 was 8-way).
// A tiles are 30 rows; MFMA A-reads of rows 30/31 overread into the NEXT pool
// region (finite garbage) and only feed discarded output rows m=30,31.
#define P_SV   0      // sv 148 fl
#define P_MKB  148    // 1 fl (ballot mask)
#define P_DH   152    // dhs [100] -> ends 252 (byte 1008, 16B aligned)
#define P_A2   252    // A2 ushort [30][136] = 2040 fl -> ends 2292 (byte 9168, 16B aligned)
#define P_A    2292   // A1 ushort [30][168] = 2520 fl -> ends 4812
#define P_VA   4812   // VAp [30][49] fp32 -> ends 6282
#define P_VB   6282   // VBu [30][96] bf16 = 1440 fl -> ends 7722
#define A1S 168
#define A2S 136
#define POOL_F 7722   // 30888 B

__global__ __launch_bounds__(256, 5)
void mpnn_fused(const float* __restrict__ h_V, const float* __restrict__ h_M,
                const int* __restrict__ mask_V, const int* __restrict__ mask_attend,
                const float* __restrict__ Wh1, const float* __restrict__ Wv1,
                const float* __restrict__ Wv2, const float* __restrict__ bs2,
                const float* __restrict__ Wv3, const float* __restrict__ bs3,
                const float* __restrict__ Wh2, const float* __restrict__ Wh3,
                const float* __restrict__ Wh4, const float* __restrict__ Wv4,
                const float* __restrict__ Ws4, const float* __restrict__ bs4,
                const float* __restrict__ Wh5, const float* __restrict__ Wv5,
                const float* __restrict__ Ws5, const float* __restrict__ bs5,
                const float* __restrict__ ln0_g, const float* __restrict__ ln0_b,
                const float* __restrict__ ln1_g, const float* __restrict__ ln1_b,
                const float* __restrict__ s1bg, const float* __restrict__ vhbg,
                const ushort* __restrict__ wsb,
                float* __restrict__ out)
{
  __shared__ float pool[POOL_F];
  float* sv   = pool + P_SV;
  float* dhs  = pool + P_DH;                 // [100]
  float* VAp  = pool + P_VA;                 // stride 49 fp32
  ushort* VBu = (ushort*)(pool + P_VB);      // [30][96] packed bf16
  ushort* A1 = (ushort*)(pool + P_A);        // [30][A1S]
  ushort* A2 = (ushort*)(pool + P_A2);       // [30][A2S]

  const int tid = threadIdx.x;
  const int node = blockIdx.x;
  const int wave = tid >> 6, lane = tid & 63;

  // ---- P0: stage node feats + edge feats + zero A K-pads + mask ballot ----
  for (int f = tid; f < F; f += 256) sv[f] = h_V[(long)node * F + f];
  {
    unsigned long long bal = __ballot(tid < KK && mask_attend[node * KK + tid] != 0);
    if (tid == 0) *(unsigned*)(pool + P_MKB) = (unsigned)bal;
  }
  // zero A1 cols 132..159 (14 dwords x 30 rows), A2 cols 116..127 (6 dwords x 30 rows)
  for (int t = tid; t < 420; t += 256) {
    int r = t / 14, c2 = t % 14;
    ((unsigned*)A1)[r * 84 + 66 + c2] = 0;
  }
  for (int t = tid; t < 180; t += 256) {
    int r = t / 6, c2 = t % 6;
    ((unsigned*)A2)[r * 68 + 58 + c2] = 0;
  }
  for (int task = tid; task < KK * 37; task += 256) {
    int k = task / 37, q = task % 37;
    float4 d = *(const float4*)(h_M + ((long)node * KK + k) * F + q * 4);
    if (q < 12) {
      VAp[k * 49 + q * 4 + 0] = d.x; VAp[k * 49 + q * 4 + 1] = d.y;
      VAp[k * 49 + q * 4 + 2] = d.z; VAp[k * 49 + q * 4 + 3] = d.w;
    } else {
      int j0 = q * 4 - 48;
      unsigned* p = (unsigned*)(A1 + k * A1S + j0);
      p[0] = (unsigned)f2bf(d.x) | ((unsigned)f2bf(d.y) << 16);
      p[1] = (unsigned)f2bf(d.z) | ((unsigned)f2bf(d.w) << 16);
    }
  }
  __syncthreads();

  // ---- P1: vh1 (240 threads, 4h each; node-half from vhbg) ----
  if (tid < 240) {
    int k = tid >> 3, h0 = (tid & 7) * 4;
    const float4* vb4 = (const float4*)(vhbg + (long)node * 96 + 3 * h0);
    float4 q0 = vb4[0], q1 = vb4[1], q2 = vb4[2];
    float a00=q0.x,a01=q0.y,a02=q0.z, a10=q0.w,a11=q1.x,a12=q1.y,
          a20=q1.z,a21=q1.w,a22=q2.x, a30=q2.y,a31=q2.z,a32=q2.w;
#pragma unroll 4
    for (int i = 0; i < 16; i++) {            // vM rows
      float v0 = VAp[k*49+3*i], v1 = VAp[k*49+3*i+1], v2 = VAp[k*49+3*i+2];
      float4 w = *(const float4*)(Wh1 + (16 + i) * 32 + h0);
      FMA3x4(v0, v1, v2, w)
    }
    unsigned* vb = (unsigned*)(VBu + k * 96 + 3 * h0);   // 3*h0 even (h0 mult of 4)
    vb[0]=pk2(a00,a01); vb[1]=pk2(a02,a10); vb[2]=pk2(a11,a12);
    vb[3]=pk2(a20,a21); vb[4]=pk2(a22,a30); vb[5]=pk2(a31,a32);
    float n0 = sqrtf(a00*a00+a01*a01+a02*a02 + 1e-8f);
    float n1 = sqrtf(a10*a10+a11*a11+a12*a12 + 1e-8f);
    float n2 = sqrtf(a20*a20+a21*a21+a22*a22 + 1e-8f);
    float n3 = sqrtf(a30*a30+a31*a31+a32*a32 + 1e-8f);
    unsigned* p = (unsigned*)(A1 + k * A1S + 100 + h0);  // vn1 cols 100..131
    p[0] = pk2(n0, n1); p[1] = pk2(n2, n3);
  }
  __syncthreads();

  // ---- P2: s1 MFMA (waves 0-1) || v1+vh2 fused (waves 2-3) ----
  if (wave < 2) {
    int r = lane & 15, q = lane >> 4;
    int nt0 = (wave == 0) ? 0 : 4, nt1 = (wave == 0) ? 4 : 7;
    for (int nt = nt0; nt < nt1; nt++) {
      int n = nt * 16 + r;
      float base = (n < 100) ? s1bg[(long)node * 100 + n] : 0.f;
      f32x4v c0 = {0,0,0,0}, c1 = {0,0,0,0};
      mfma_nt2<5>(A1, A1S, wsb + B1HI + n * 160, wsb + B1LO + n * 160, lane, c0, c1);
      unsigned* dst = (unsigned*)A2;
#pragma unroll
      for (int reg = 0; reg < 4; reg++) {
        int m0 = q * 4 + reg, m1 = m0 + 16;
        unsigned hx = f2bf(fmaxf(c0[reg] + base, 0.f));
        unsigned ox = __shfl_down(hx, 1);
        unsigned hy = f2bf(fmaxf(c1[reg] + base, 0.f));
        unsigned oy = __shfl_down(hy, 1);
        if (((lane & 1) == 0) && n < 100) {
          dst[(m0 * A2S + n) >> 1] = hx | (ox << 16);
          if (m1 < 30) dst[(m1 * A2S + n) >> 1] = hy | (oy << 16);
        }
      }
    }
  } else {
    int vt = tid - 128;
    if (vt < 120) {
      int k = vt >> 2, c = vt & 3, h0 = c * 4;
      v_vh_fused<32>((const unsigned*)(VBu + k * 96), Wv1 + h0, Wh2, c, h0,
                     (unsigned*)(VBu + k * 96), A2 + k * A2S + 100 + h0);
    }
  }
  __syncthreads();

  // ---- P4: s2 MFMA (waves 0-1) || v2+vh3 fused (waves 2-3) || zero A1 cols 116..127 ----
  if (wave < 2) {
    int r = lane & 15, q = lane >> 4;
    int nt0 = (wave == 0) ? 0 : 4, nt1 = (wave == 0) ? 4 : 7;
    for (int nt = nt0; nt < nt1; nt++) {
      f32x4v c0 = {0,0,0,0}, c1 = {0,0,0,0};
      int n = nt * 16 + r;
      mfma_nt2<4>(A2, A2S, wsb + B2HI + n * 128, wsb + B2LO + n * 128, lane, c0, c1);
      float base = (n < 100) ? bs2[n] : 0.f;
      unsigned* dst = (unsigned*)A1;
#pragma unroll
      for (int reg = 0; reg < 4; reg++) {
        int m0 = q * 4 + reg, m1 = m0 + 16;
        unsigned hx = f2bf(fmaxf(c0[reg] + base, 0.f));
        unsigned ox = __shfl_down(hx, 1);
        unsigned hy = f2bf(fmaxf(c1[reg] + base, 0.f));
        unsigned oy = __shfl_down(hy, 1);
        if (((lane & 1) == 0) && n < 100) {
          dst[(m0 * A1S + n) >> 1] = hx | (ox << 16);
          if (m1 < 30) dst[(m1 * A1S + n) >> 1] = hy | (oy << 16);
        }
      }
    }
  } else {
    int vt = tid - 128;
    if (vt < 120) {
      int k = vt >> 2, c = vt & 3, h0 = c * 4;
      v_vh_fused<16>((const unsigned*)(VBu + k * 96), Wv2 + h0, Wh3, c, h0,
                     (unsigned*)(VBu + k * 96), A1 + k * A1S + 100 + h0);
    } else {
      // tids 248..255: zero A1 cols 116..127 for s3 (disjoint from MFMA's cols 0..99
      // and the fused task's norm cols 100..115; A1 is not read this phase)
      for (int t = vt - 120; t < 180; t += 8) {
        int r = t / 6, c2 = t % 6;
        ((unsigned*)A1)[r * 84 + 58 + c2] = 0;
      }
    }
  }
  __syncthreads();

  // ---- P6: s3 MFMA with in-epilogue masked K-reduction -> dhs[n] (waves 0-1) || v3 (waves 2-3) ----
  if (wave < 2) {
    unsigned mkb = *(unsigned*)(pool + P_MKB);   // bits 30,31 are 0 -> garbage rows self-excluded
    int r = lane & 15, q = lane >> 4;
    int nt0 = (wave == 0) ? 0 : 4, nt1 = (wave == 0) ? 4 : 7;
    for (int nt = nt0; nt < nt1; nt++) {
      f32x4v c0 = {0,0,0,0}, c1 = {0,0,0,0};
      int n = nt * 16 + r;
      mfma_nt2<4>(A1, A1S, wsb + B3HI + n * 128, wsb + B3LO + n * 128, lane, c0, c1);
      float part = 0.f;
#pragma unroll
      for (int reg = 0; reg < 4; reg++) {
        int m0 = q * 4 + reg, m1 = m0 + 16;
        part += ((mkb >> m0) & 1) ? c0[reg] : 0.f;
        part += ((mkb >> m1) & 1) ? c1[reg] : 0.f;
      }
      part += __shfl_xor(part, 16);   // sum across q-groups (lanes r, r+16, r+32, r+48)
      part += __shfl_xor(part, 32);
      if (q == 0 && n < 100) dhs[n] = part;   // = sum_k mask_k * c[k][n]
    }
  } else {
    int vt = tid - 128;
    if (vt < 120) { int k = vt >> 2, o0 = (vt & 3) * 4;
      vtaskb<16, false>((const unsigned*)(VBu + k * 96), Wv3 + o0, 16, VAp + k*49 + 3*o0); }
  }
  __syncthreads();

  // ---- node phase scratch aliases A1 region (dead after P6; 2032 fl <= 2520) ----
  float* ns   = pool + P_A;
  float* xb   = ns;          // 148
  float* hb   = ns + 160;    // 148
  float* nvh4 = ns + 320;    // 96
  float* nvn4 = ns + 416;    // 32
  float* s4   = ns + 448;    // 400 (+32 vn5 at 848 -> contiguous 432)
  float* nvn5 = ns + 848;    // 32
  float* v4   = ns + 880;    // 96
  float* nvh5 = ns + 976;    // 96
  float* v5   = ns + 1072;   // 48
  float* s5   = ns + 1120;   // 100
  float* red  = ns + 1220;   // 4
  float* part = ns + 1232;   // 800  (ends 2032)

  // ---- P7: masked mean over K -> xb = sv + dh ----
  {
    unsigned mkb = *(unsigned*)(pool + P_MKB);
    float cntf = (float)__popc(mkb);
    for (int f = tid; f < F; f += 256) {
      float acc;
      if (f < 48) { acc = 0.f; for (int k = 0; k < KK; k++) if ((mkb >> k) & 1) acc += VAp[k*49 + f]; }
      else        { int j = f - 48; acc = dhs[j] + cntf * bs3[j]; }
      xb[f] = sv[f] + acc * (1.f / (float)KK);
    }
  }
  __syncthreads();
  // ln0 stats via wave shuffles
  if (tid < 64) {
    float a = (tid < 50) ? xb[48 + 2 * tid] : 0.f;
    float b = (tid < 50) ? xb[48 + 2 * tid + 1] : 0.f;
    float s = a + b, qq = a * a + b * b;
    for (int off = 32; off; off >>= 1) { s += __shfl_down(s, off); qq += __shfl_down(qq, off); }
    if (tid == 0) { red[1] = s * 0.01f; red[2] = qq * 0.01f; }
  } else if (tid < 128) {
    int l = tid - 64;
    float v = (l < 48) ? xb[l] : 0.f;
    float qq = v * v;
    for (int off = 32; off; off >>= 1) qq += __shfl_down(qq, off);
    if (l == 0) red[0] = sqrtf(qq * (1.f / 16.f) + 1e-8f);
  }
  __syncthreads();
  {
    float denom = red[0], mu = red[1];
    float var = red[2] - mu * mu;
    float rs = rsqrtf(var + 1e-5f);
    for (int f = tid; f < F; f += 256) {
      if (f < 48) hb[f] = xb[f] / denom;
      else { int j = f - 48; hb[f] = (xb[f] - mu) * rs * ln0_g[j] + ln0_b[j]; }
    }
  }
  __syncthreads();

  // GVP4: vh4 (16 -> 32), 32 threads, 1 h each
  if (tid < 32) {
    int h = tid;
    float a0 = 0.f, a1 = 0.f, a2 = 0.f;
#pragma unroll 4
    for (int i = 0; i < 16; i++) {
      float w = Wh4[i * 32 + h];
      a0 = fmaf(hb[3*i], w, a0); a1 = fmaf(hb[3*i+1], w, a1); a2 = fmaf(hb[3*i+2], w, a2);
    }
    nvh4[3*h] = a0; nvh4[3*h+1] = a1; nvh4[3*h+2] = a2;
    nvn4[h] = sqrtf(a0*a0 + a1*a1 + a2*a2 + 1e-8f);
  }
  __syncthreads();
  // s_out4 (400 outs, dot 132, relu; 200 threads x 2 cols) || v4 (32 threads, wave 3)
  if (tid < 200) {
    int j0 = tid * 2;
    float ax = bs4[j0], ay = bs4[j0 + 1];
    const float* w = Ws4 + j0;
#pragma unroll 10
    for (int i = 0; i < 100; i++) {
      float s = hb[48 + i];
      float2 w2 = *(const float2*)(w + i * 400);
      ax = fmaf(s, w2.x, ax); ay = fmaf(s, w2.y, ay);
    }
#pragma unroll 8
    for (int h = 0; h < 32; h++) {
      float s = nvn4[h];
      float2 w2 = *(const float2*)(w + (100 + h) * 400);
      ax = fmaf(s, w2.x, ax); ay = fmaf(s, w2.y, ay);
    }
    s4[j0] = fmaxf(ax, 0.f); s4[j0 + 1] = fmaxf(ay, 0.f);
  } else if (tid >= 224) {
    int o = tid - 224;
    float a0 = 0.f, a1 = 0.f, a2 = 0.f;
#pragma unroll 4
    for (int h = 0; h < 32; h++) {
      float w = Wv4[h * 32 + o];
      a0 = fmaf(nvh4[3*h], w, a0); a1 = fmaf(nvh4[3*h+1], w, a1); a2 = fmaf(nvh4[3*h+2], w, a2);
    }
    GATE3(a0, a1, a2, v4[3*o], v4[3*o+1], v4[3*o+2])
  }
  __syncthreads();
  // GVP5: vh5 (32 -> 32), 32 threads
  if (tid < 32) {
    int h = tid;
    float a0 = 0.f, a1 = 0.f, a2 = 0.f;
#pragma unroll 4
    for (int i = 0; i < 32; i++) {
      float w = Wh5[i * 32 + h];
      a0 = fmaf(v4[3*i], w, a0); a1 = fmaf(v4[3*i+1], w, a1); a2 = fmaf(v4[3*i+2], w, a2);
    }
    nvh5[3*h] = a0; nvh5[3*h+1] = a1; nvh5[3*h+2] = a2;
    nvn5[h] = sqrtf(a0*a0 + a1*a1 + a2*a2 + 1e-8f);
  }
  __syncthreads();
  // s_out5 partials (dot 432 split 8 ways, 200 threads) || v5 (16 threads, wave 3)
  if (tid < 200) {
    int jq = tid / 8, c = tid % 8, j0 = jq * 4;
    int ibeg = c * 54, iend = ibeg + 54;
    float4 acc = make_float4(0.f, 0.f, 0.f, 0.f);
    const float* w = Ws5 + j0;
#pragma unroll 6
    for (int i = ibeg; i < iend; i++) {
      float s = s4[i];  // s4[0..399] then nvn5[0..31], contiguous
      float4 w4 = *(const float4*)(w + i * 100);
      acc.x = fmaf(s, w4.x, acc.x); acc.y = fmaf(s, w4.y, acc.y);
      acc.z = fmaf(s, w4.z, acc.z); acc.w = fmaf(s, w4.w, acc.w);
    }
    *(float4*)&part[tid * 4] = acc;
  } else if (tid >= 224 && tid < 240) {
    int o = tid - 224;
    float a0 = 0.f, a1 = 0.f, a2 = 0.f;
#pragma unroll 4
    for (int h = 0; h < 32; h++) {
      float w = Wv5[h * 16 + o];
      a0 = fmaf(nvh5[3*h], w, a0); a1 = fmaf(nvh5[3*h+1], w, a1); a2 = fmaf(nvh5[3*h+2], w, a2);
    }
    v5[3*o] = a0; v5[3*o+1] = a1; v5[3*o+2] = a2;
  }
  __syncthreads();
  if (tid < 25) {
    int j0 = tid * 4;
    float4 b = *(const float4*)(bs5 + j0);
    float4 acc = b;
#pragma unroll
    for (int c = 0; c < 8; c++) {
      float4 p = *(const float4*)&part[(tid * 8 + c) * 4];
      acc.x += p.x; acc.y += p.y; acc.z += p.z; acc.w += p.w;
    }
    *(float4*)&s5[j0] = acc;
  }
  __syncthreads();
  // x2 = h + dh2
  for (int f = tid; f < F; f += 256) {
    float d = (f < 48) ? v5[f] : s5[f - 48];
    xb[f] = hb[f] + d;
  }
  __syncthreads();
  // ln1 stats
  if (tid < 64) {
    float a = (tid < 50) ? xb[48 + 2 * tid] : 0.f;
    float b = (tid < 50) ? xb[48 + 2 * tid + 1] : 0.f;
    float s = a + b, qq = a * a + b * b;
    for (int off = 32; off; off >>= 1) { s += __shfl_down(s, off); qq += __shfl_down(qq, off); }
    if (tid == 0) { red[1] = s * 0.01f; red[2] = qq * 0.01f; }
  } else if (tid < 128) {
    int l = tid - 64;
    float v = (l < 48) ? xb[l] : 0.f;
    float qq = v * v;
    for (int off = 32; off; off >>= 1) qq += __shfl_down(qq, off);
    if (l == 0) red[0] = sqrtf(qq * (1.f / 16.f) + 1e-8f);
  }
  __syncthreads();
  {
    float denom = red[0], mu = red[1];
    float var = red[2] - mu * mu;
    float rs = rsqrtf(var + 1e-5f);
    float mv = (float)mask_V[node];
    for (int f = tid; f < F; f += 256) {
      float val;
      if (f < 48) val = xb[f] / denom;
      else { int j = f - 48; val = (xb[f] - mu) * rs * ln1_g[j] + ln1_b[j]; }
      out[(long)node * F + f] = mv * val;
    }
  }
}

extern "C" void kernel_launch(void* const* d_in, const int* in_sizes, int n_in,
                              void* d_out, int out_size, void* d_ws, size_t ws_size,
                              hipStream_t stream) {
  const float* h_V  = (const float*)d_in[0];
  const float* h_M  = (const float*)d_in[1];
  const int* mask_V = (const int*)d_in[2];
  const int* mask_attend = (const int*)d_in[3];
  const float* Wh1 = (const float*)d_in[4];
  const float* Wv1 = (const float*)d_in[5];
  const float* Ws1 = (const float*)d_in[6];
  const float* bs1 = (const float*)d_in[7];
  const float* Wh2 = (const float*)d_in[8];
  const float* Wv2 = (const float*)d_in[9];
  const float* Ws2 = (const float*)d_in[10];
  const float* bs2 = (const float*)d_in[11];
  const float* Wh3 = (const float*)d_in[12];
  const float* Wv3 = (const float*)d_in[13];
  const float* Ws3 = (const float*)d_in[14];
  const float* bs3 = (const float*)d_in[15];
  const float* Wh4 = (const float*)d_in[16];
  const float* Wv4 = (const float*)d_in[17];
  const float* Ws4 = (const float*)d_in[18];
  const float* bs4 = (const float*)d_in[19];
  const float* Wh5 = (const float*)d_in[20];
  const float* Wv5 = (const float*)d_in[21];
  const float* Ws5 = (const float*)d_in[22];
  const float* bs5 = (const float*)d_in[23];
  const float* ln0_g = (const float*)d_in[24];
  const float* ln0_b = (const float*)d_in[25];
  const float* ln1_g = (const float*)d_in[26];
  const float* ln1_b = (const float*)d_in[27];
  float* out = (float*)d_out;

  float* wsf = (float*)d_ws;
  float* s1bg = wsf + WS_S1B;
  float* vhbg = wsf + WS_VHB;
  ushort* wsb = (ushort*)(wsf + WS_WSB);

  prep_weights<<<dim3(182), dim3(256), 0, stream>>>(Ws1, Ws2, Ws3, wsb);
  prep_node<<<dim3(NNODE / NPB), dim3(256), 0, stream>>>(h_V, Ws1, bs1, Wh1, s1bg, vhbg);
  mpnn_fused<<<dim3(NNODE), dim3(256), 0, stream>>>(
      h_V, h_M, mask_V, mask_attend,
      Wh1, Wv1, Wv2, bs2, Wv3, bs3, Wh2, Wh3,
      Wh4, Wv4, Ws4, bs4, Wh5, Wv5, Ws5, bs5,
      ln0_g, ln0_b, ln1_g, ln1_b, s1bg, vhbg, wsb, out);
}

// Round 3
// 1327.466 us; speedup vs baseline: 1.0355x; 1.0355x over previous
//
#include <hip/hip_runtime.h>

#define KK 30
#define F 148
#define NNODE 16384
#define NPB 16   // nodes per prep_node block

typedef short bf16x8 __attribute__((ext_vector_type(8)));
typedef float f32x4v __attribute__((ext_vector_type(4)));

// ---- bf16 helpers (RNE) ----
__device__ __forceinline__ ushort f2bf(float x) {
  unsigned u = __float_as_uint(x);
  unsigned r = (u + 0x7FFF + ((u >> 16) & 1)) >> 16;
  return (ushort)r;
}
__device__ __forceinline__ float bf2f(ushort b) { return __uint_as_float(((unsigned)b) << 16); }
__device__ __forceinline__ unsigned pk2(float x, float y) {
  return (unsigned)f2bf(x) | ((unsigned)f2bf(y) << 16);
}
__device__ __forceinline__ void bsplit(float x, ushort& h, ushort& l) {
  ushort hh = f2bf(x); h = hh; l = f2bf(x - bf2f(hh));
}

// d_ws layout: [ s1bg 16384*100 fl ][ vhbg 16384*96 fl ][ wsb ushorts ]
#define WS_S1B 0
#define WS_VHB (NNODE * 100)
#define WS_WSB (NNODE * 100 + NNODE * 96)
// wsb (ushort offsets): pre-transposed split weights Bt[n][k], hi+lo
#define B1HI 0
#define B1LO 17920   // 112*160
#define B2HI 35840
#define B2LO 50176   // 112*128
#define B3HI 64512
#define B3LO 78848

__global__ void prep_weights(const float* __restrict__ Ws1, const float* __restrict__ Ws2,
                             const float* __restrict__ Ws3, ushort* __restrict__ ws) {
  int i = blockIdx.x * 256 + threadIdx.x;
  if (i < 17920) {                       // B1: [112][160], src rows 100..231 of Ws1 [232][100]
    int n = i / 160, k = i % 160;
    float w = (n < 100 && k < 132) ? Ws1[(100 + k) * 100 + n] : 0.f;
    ushort h, l; bsplit(w, h, l);
    ws[B1HI + i] = h; ws[B1LO + i] = l;
  } else if (i < 17920 + 14336) {        // B2: [112][128], src Ws2 [116][100]
    int j = i - 17920; int n = j / 128, k = j % 128;
    float w = (n < 100 && k < 116) ? Ws2[k * 100 + n] : 0.f;
    ushort h, l; bsplit(w, h, l);
    ws[B2HI + j] = h; ws[B2LO + j] = l;
  } else if (i < 17920 + 2 * 14336) {    // B3: [112][128], src Ws3 [116][100]
    int j = i - 17920 - 14336; int n = j / 128, k = j % 128;
    float w = (n < 100 && k < 116) ? Ws3[k * 100 + n] : 0.f;
    ushort h, l; bsplit(w, h, l);
    ws[B3HI + j] = h; ws[B3LO + j] = l;
  }
}

// per-node k-independent precompute, 16 nodes per block with Ws1^T staged in LDS.
__global__ __launch_bounds__(256)
void prep_node(const float* __restrict__ h_V, const float* __restrict__ Ws1,
               const float* __restrict__ bs1, const float* __restrict__ Wh1,
               float* __restrict__ s1bg, float* __restrict__ vhbg) {
  __shared__ float wt[100 * 101];   // Ws1^T [n][i], pad 101 -> conflict-free column reads
  __shared__ float wh[512];         // Wh1 [16][32]
  __shared__ float svs[NPB * 148];
  const int tid = threadIdx.x;
  const long node0 = (long)blockIdx.x * NPB;
  for (int idx = tid; idx < 10000; idx += 256) {
    int i = idx / 100, n = idx - i * 100;
    wt[n * 101 + i] = Ws1[idx];     // coalesced read, scattered LDS write
  }
  for (int idx = tid; idx < 512; idx += 256) wh[idx] = Wh1[idx];
  for (int idx = tid; idx < NPB * 148; idx += 256) {
    int nd = idx / 148, f = idx - nd * 148;
    svs[idx] = h_V[(node0 + nd) * 148 + f];
  }
  __syncthreads();
  for (int task = tid; task < NPB * 100; task += 256) {
    int nd = task / 100, n = task - nd * 100;
    const float* s = svs + nd * 148 + 48;
    const float* w = wt + n * 101;
    float acc = bs1[n];
#pragma unroll 10
    for (int i = 0; i < 100; i++) acc = fmaf(s[i], w[i], acc);
    s1bg[(node0 + nd) * 100 + n] = acc;
  }
  for (int task = tid; task < NPB * 32; task += 256) {
    int nd = task >> 5, h = task & 31;
    const float* s = svs + nd * 148;
    float a0 = 0.f, a1 = 0.f, a2 = 0.f;
#pragma unroll 4
    for (int i = 0; i < 16; i++) {
      float w = wh[i * 32 + h];
      a0 = fmaf(s[3*i], w, a0); a1 = fmaf(s[3*i+1], w, a1); a2 = fmaf(s[3*i+2], w, a2);
    }
    vhbg[(node0 + nd) * 96 + 3*h + 0] = a0;
    vhbg[(node0 + nd) * 96 + 3*h + 1] = a1;
    vhbg[(node0 + nd) * 96 + 3*h + 2] = a2;
  }
}

#define DECL12 float a00=0,a01=0,a02=0,a10=0,a11=0,a12=0,a20=0,a21=0,a22=0,a30=0,a31=0,a32=0;
#define FMA3x4(v0_,v1_,v2_,w_) \
  a00=fmaf(v0_,w_.x,a00); a01=fmaf(v1_,w_.x,a01); a02=fmaf(v2_,w_.x,a02); \
  a10=fmaf(v0_,w_.y,a10); a11=fmaf(v1_,w_.y,a11); a12=fmaf(v2_,w_.y,a12); \
  a20=fmaf(v0_,w_.z,a20); a21=fmaf(v1_,w_.z,a21); a22=fmaf(v2_,w_.z,a22); \
  a30=fmaf(v0_,w_.w,a30); a31=fmaf(v1_,w_.w,a31); a32=fmaf(v2_,w_.w,a32);

#define GATE3(x0,x1,x2,d0,d1,d2) { float vn_=sqrtf((x0)*(x0)+(x1)*(x1)+(x2)*(x2)+1e-8f); \
  float g_=1.f/(1.f+expf(-vn_)); d0=(x0)*g_; d1=(x1)*g_; d2=(x2)*g_; }

// vector-path matvec, 4 outputs, bf16-packed source (VBu), fp32 dest
template<int NI, bool GATEF>
__device__ __forceinline__ void vtaskb(const unsigned* __restrict__ vsrc,
                                       const float* __restrict__ wbase, int wstride,
                                       float* __restrict__ vdst)
{
  DECL12
#pragma unroll 4
  for (int h2 = 0; h2 < NI / 2; h2++) {
    unsigned d0 = vsrc[3*h2+0], d1 = vsrc[3*h2+1], d2 = vsrc[3*h2+2];
    float4 w0 = *(const float4*)(wbase + (2*h2) * wstride);
    float4 w1 = *(const float4*)(wbase + (2*h2+1) * wstride);
    float e0 = bf2f((ushort)d0), e1 = bf2f((ushort)(d0 >> 16)), e2 = bf2f((ushort)d1);
    float g0 = bf2f((ushort)(d1 >> 16)), g1 = bf2f((ushort)d2), g2 = bf2f((ushort)(d2 >> 16));
    FMA3x4(e0, e1, e2, w0)
    FMA3x4(g0, g1, g2, w1)
  }
  if (GATEF) {
    GATE3(a00,a01,a02, vdst[0],vdst[1],vdst[2])
    GATE3(a10,a11,a12, vdst[3],vdst[4],vdst[5])
    GATE3(a20,a21,a22, vdst[6],vdst[7],vdst[8])
    GATE3(a30,a31,a32, vdst[9],vdst[10],vdst[11])
  } else {
    vdst[0]=a00; vdst[1]=a01; vdst[2]=a02;  vdst[3]=a10; vdst[4]=a11; vdst[5]=a12;
    vdst[6]=a20; vdst[7]=a21; vdst[8]=a22;  vdst[9]=a30; vdst[10]=a31; vdst[11]=a32;
  }
}

// Fused: gated v-task (NI inputs -> 16 outputs, this thread owns o0=c*4..c*4+3)
// + next-stage vh (16 -> 16) via 4-lane xor exchange of the gated values.
// R3: NO local arrays — named scalars only, fully hand-unrolled exchange.
// (R2's gg[12]/t[12] arrays went to scratch: +200 MB HBM writes per dispatch.)
// No __restrict__ on vsrc/vrow_u: they alias (read-before-write is enforced by
// the data dependency: every written value depends on all reads of the row).
template<int NI>
__device__ __forceinline__ void v_vh_fused(const unsigned* vsrc,
                                           const float* __restrict__ Wv,   // pre-offset by o0
                                           const float* __restrict__ Whn,  // [16][16]
                                           int c, int h0,
                                           unsigned* vrow_u, ushort* ncol)
{
  DECL12
#pragma unroll
  for (int h2 = 0; h2 < NI / 2; h2++) {
    unsigned d0 = vsrc[3*h2+0], d1 = vsrc[3*h2+1], d2 = vsrc[3*h2+2];
    float4 w0 = *(const float4*)(Wv + (2*h2) * 16);
    float4 w1 = *(const float4*)(Wv + (2*h2+1) * 16);
    float e0 = bf2f((ushort)d0), e1 = bf2f((ushort)(d0 >> 16)), e2 = bf2f((ushort)d1);
    float f0 = bf2f((ushort)(d1 >> 16)), f1 = bf2f((ushort)d2), f2 = bf2f((ushort)(d2 >> 16));
    FMA3x4(e0, e1, e2, w0)
    FMA3x4(f0, f1, f2, w1)
  }
  float g0,g1,g2,g3,g4,g5,g6,g7,g8,g9,g10,g11;
  GATE3(a00,a01,a02, g0,g1,g2)
  GATE3(a10,a11,a12, g3,g4,g5)
  GATE3(a20,a21,a22, g6,g7,g8)
  GATE3(a30,a31,a32, g9,g10,g11)
  a00=0;a01=0;a02=0;a10=0;a11=0;a12=0;a20=0;a21=0;a22=0;a30=0;a31=0;a32=0;
  {   // m = 0: own gated values, weight rows c*4..c*4+3
    int ob = c * 4;
    float4 w;
    w = *(const float4*)(Whn + (ob+0)*16 + h0); FMA3x4(g0,g1,g2,w)
    w = *(const float4*)(Whn + (ob+1)*16 + h0); FMA3x4(g3,g4,g5,w)
    w = *(const float4*)(Whn + (ob+2)*16 + h0); FMA3x4(g6,g7,g8,w)
    w = *(const float4*)(Whn + (ob+3)*16 + h0); FMA3x4(g9,g10,g11,w)
  }
#define XCH_ACC(m_) { \
    float t0=__shfl_xor(g0,m_),  t1=__shfl_xor(g1,m_),  t2=__shfl_xor(g2,m_), \
          t3=__shfl_xor(g3,m_),  t4=__shfl_xor(g4,m_),  t5=__shfl_xor(g5,m_), \
          t6=__shfl_xor(g6,m_),  t7=__shfl_xor(g7,m_),  t8=__shfl_xor(g8,m_), \
          t9=__shfl_xor(g9,m_), t10=__shfl_xor(g10,m_), t11=__shfl_xor(g11,m_); \
    int ob = (c ^ m_) * 4; \
    float4 w; \
    w = *(const float4*)(Whn + (ob+0)*16 + h0); FMA3x4(t0,t1,t2,w) \
    w = *(const float4*)(Whn + (ob+1)*16 + h0); FMA3x4(t3,t4,t5,w) \
    w = *(const float4*)(Whn + (ob+2)*16 + h0); FMA3x4(t6,t7,t8,w) \
    w = *(const float4*)(Whn + (ob+3)*16 + h0); FMA3x4(t9,t10,t11,w) }
  XCH_ACC(1)
  XCH_ACC(2)
  XCH_ACC(3)
#undef XCH_ACC
  unsigned* vb = vrow_u + ((3 * h0) >> 1);
  vb[0]=pk2(a00,a01); vb[1]=pk2(a02,a10); vb[2]=pk2(a11,a12);
  vb[3]=pk2(a20,a21); vb[4]=pk2(a22,a30); vb[5]=pk2(a31,a32);
  float n0 = sqrtf(a00*a00+a01*a01+a02*a02 + 1e-8f);
  float n1 = sqrtf(a10*a10+a11*a11+a12*a12 + 1e-8f);
  float n2 = sqrtf(a20*a20+a21*a21+a22*a22 + 1e-8f);
  float n3 = sqrtf(a30*a30+a31*a31+a32*a32 + 1e-8f);
  unsigned* p = (unsigned*)ncol;
  p[0] = pk2(n0, n1); p[1] = pk2(n2, n3);
}

// 2-term split-bf16 MFMA over one n-tile, two m-tiles. A hi-only from LDS; B hi+lo from L2.
template<int NKS>
__device__ __forceinline__ void mfma_nt2(const ushort* __restrict__ A, int astr,
                                         const ushort* __restrict__ B_hi,
                                         const ushort* __restrict__ B_lo,
                                         int lane, f32x4v& c0, f32x4v& c1)
{
  int r = lane & 15, q = lane >> 4;
  const int ka = q * 8;
#pragma unroll
  for (int ks = 0; ks < NKS; ks++) {
    int ko = ka + ks * 32;
    bf16x8 a0 = *(const bf16x8*)(A + r * astr + ko);
    bf16x8 a1 = *(const bf16x8*)(A + (16 + r) * astr + ko);
    bf16x8 bh = *(const bf16x8*)(B_hi + ko);
    bf16x8 bl = *(const bf16x8*)(B_lo + ko);
    c0 = __builtin_amdgcn_mfma_f32_16x16x32_bf16(a0, bh, c0, 0, 0, 0);
    c0 = __builtin_amdgcn_mfma_f32_16x16x32_bf16(a0, bl, c0, 0, 0, 0);
    c1 = __builtin_amdgcn_mfma_f32_16x16x32_bf16(a1, bh, c1, 0, 0, 0);
    c1 = __builtin_amdgcn_mfma_f32_16x16x32_bf16(a1, bl, c1, 0, 0, 0);
  }
}

// LDS pool carving (float offsets), 30888 B -> 5 blocks/CU.
// A1 stride 168 ushorts (336B: 2-way bank alias = free; 160 was 8-way).
// A tiles are 30 rows; MFMA A-reads of rows 30/31 overread into the NEXT pool
// region (finite garbage) and only feed discarded output rows m=30,31.
#define P_SV   0      // sv 148 fl
#define P_MKB  148    // 1 fl (ballot mask)
#define P_DH   152    // dhs [100] -> ends 252 (byte 1008, 16B aligned)
#define P_A2   252    // A2 ushort [30][136] = 2040 fl -> ends 2292 (byte 9168, 16B aligned)
#define P_A    2292   // A1 ushort [30][168] = 2520 fl -> ends 4812
#define P_VA   4812   // VAp [30][49] fp32 -> ends 6282
#define P_VB   6282   // VBu [30][96] bf16 = 1440 fl -> ends 7722
#define A1S 168
#define A2S 136
#define POOL_F 7722   // 30888 B

__global__ __launch_bounds__(256, 5)
void mpnn_fused(const float* __restrict__ h_V, const float* __restrict__ h_M,
                const int* __restrict__ mask_V, const int* __restrict__ mask_attend,
                const float* __restrict__ Wh1, const float* __restrict__ Wv1,
                const float* __restrict__ Wv2, const float* __restrict__ bs2,
                const float* __restrict__ Wv3, const float* __restrict__ bs3,
                const float* __restrict__ Wh2, const float* __restrict__ Wh3,
                const float* __restrict__ Wh4, const float* __restrict__ Wv4,
                const float* __restrict__ Ws4, const float* __restrict__ bs4,
                const float* __restrict__ Wh5, const float* __restrict__ Wv5,
                const float* __restrict__ Ws5, const float* __restrict__ bs5,
                const float* __restrict__ ln0_g, const float* __restrict__ ln0_b,
                const float* __restrict__ ln1_g, const float* __restrict__ ln1_b,
                const float* __restrict__ s1bg, const float* __restrict__ vhbg,
                const ushort* __restrict__ wsb,
                float* __restrict__ out)
{
  __shared__ float pool[POOL_F];
  float* sv   = pool + P_SV;
  float* dhs  = pool + P_DH;                 // [100]
  float* VAp  = pool + P_VA;                 // stride 49 fp32
  ushort* VBu = (ushort*)(pool + P_VB);      // [30][96] packed bf16
  ushort* A1 = (ushort*)(pool + P_A);        // [30][A1S]
  ushort* A2 = (ushort*)(pool + P_A2);       // [30][A2S]

  const int tid = threadIdx.x;
  const int node = blockIdx.x;
  const int wave = tid >> 6, lane = tid & 63;

  // ---- P0: stage node feats + edge feats + zero A K-pads + mask ballot ----
  for (int f = tid; f < F; f += 256) sv[f] = h_V[(long)node * F + f];
  {
    unsigned long long bal = __ballot(tid < KK && mask_attend[node * KK + tid] != 0);
    if (tid == 0) *(unsigned*)(pool + P_MKB) = (unsigned)bal;
  }
  // zero A1 cols 132..159 (14 dwords x 30 rows), A2 cols 116..127 (6 dwords x 30 rows)
  for (int t = tid; t < 420; t += 256) {
    int r = t / 14, c2 = t % 14;
    ((unsigned*)A1)[r * 84 + 66 + c2] = 0;
  }
  for (int t = tid; t < 180; t += 256) {
    int r = t / 6, c2 = t % 6;
    ((unsigned*)A2)[r * 68 + 58 + c2] = 0;
  }
  for (int task = tid; task < KK * 37; task += 256) {
    int k = task / 37, q = task % 37;
    float4 d = *(const float4*)(h_M + ((long)node * KK + k) * F + q * 4);
    if (q < 12) {
      VAp[k * 49 + q * 4 + 0] = d.x; VAp[k * 49 + q * 4 + 1] = d.y;
      VAp[k * 49 + q * 4 + 2] = d.z; VAp[k * 49 + q * 4 + 3] = d.w;
    } else {
      int j0 = q * 4 - 48;
      unsigned* p = (unsigned*)(A1 + k * A1S + j0);
      p[0] = (unsigned)f2bf(d.x) | ((unsigned)f2bf(d.y) << 16);
      p[1] = (unsigned)f2bf(d.z) | ((unsigned)f2bf(d.w) << 16);
    }
  }
  __syncthreads();

  // ---- P1: vh1 (240 threads, 4h each; node-half from vhbg) ----
  if (tid < 240) {
    int k = tid >> 3, h0 = (tid & 7) * 4;
    const float4* vb4 = (const float4*)(vhbg + (long)node * 96 + 3 * h0);
    float4 q0 = vb4[0], q1 = vb4[1], q2 = vb4[2];
    float a00=q0.x,a01=q0.y,a02=q0.z, a10=q0.w,a11=q1.x,a12=q1.y,
          a20=q1.z,a21=q1.w,a22=q2.x, a30=q2.y,a31=q2.z,a32=q2.w;
#pragma unroll 4
    for (int i = 0; i < 16; i++) {            // vM rows
      float v0 = VAp[k*49+3*i], v1 = VAp[k*49+3*i+1], v2 = VAp[k*49+3*i+2];
      float4 w = *(const float4*)(Wh1 + (16 + i) * 32 + h0);
      FMA3x4(v0, v1, v2, w)
    }
    unsigned* vb = (unsigned*)(VBu + k * 96 + 3 * h0);   // 3*h0 even (h0 mult of 4)
    vb[0]=pk2(a00,a01); vb[1]=pk2(a02,a10); vb[2]=pk2(a11,a12);
    vb[3]=pk2(a20,a21); vb[4]=pk2(a22,a30); vb[5]=pk2(a31,a32);
    float n0 = sqrtf(a00*a00+a01*a01+a02*a02 + 1e-8f);
    float n1 = sqrtf(a10*a10+a11*a11+a12*a12 + 1e-8f);
    float n2 = sqrtf(a20*a20+a21*a21+a22*a22 + 1e-8f);
    float n3 = sqrtf(a30*a30+a31*a31+a32*a32 + 1e-8f);
    unsigned* p = (unsigned*)(A1 + k * A1S + 100 + h0);  // vn1 cols 100..131
    p[0] = pk2(n0, n1); p[1] = pk2(n2, n3);
  }
  __syncthreads();

  // ---- P2: s1 MFMA (waves 0-1) || v1+vh2 fused (waves 2-3) ----
  if (wave < 2) {
    int r = lane & 15, q = lane >> 4;
    int nt0 = (wave == 0) ? 0 : 4, nt1 = (wave == 0) ? 4 : 7;
    for (int nt = nt0; nt < nt1; nt++) {
      int n = nt * 16 + r;
      float base = (n < 100) ? s1bg[(long)node * 100 + n] : 0.f;
      f32x4v c0 = {0,0,0,0}, c1 = {0,0,0,0};
      mfma_nt2<5>(A1, A1S, wsb + B1HI + n * 160, wsb + B1LO + n * 160, lane, c0, c1);
      unsigned* dst = (unsigned*)A2;
#pragma unroll
      for (int reg = 0; reg < 4; reg++) {
        int m0 = q * 4 + reg, m1 = m0 + 16;
        unsigned hx = f2bf(fmaxf(c0[reg] + base, 0.f));
        unsigned ox = __shfl_down(hx, 1);
        unsigned hy = f2bf(fmaxf(c1[reg] + base, 0.f));
        unsigned oy = __shfl_down(hy, 1);
        if (((lane & 1) == 0) && n < 100) {
          dst[(m0 * A2S + n) >> 1] = hx | (ox << 16);
          if (m1 < 30) dst[(m1 * A2S + n) >> 1] = hy | (oy << 16);
        }
      }
    }
  } else {
    int vt = tid - 128;
    if (vt < 120) {
      int k = vt >> 2, c = vt & 3, h0 = c * 4;
      v_vh_fused<32>((const unsigned*)(VBu + k * 96), Wv1 + h0, Wh2, c, h0,
                     (unsigned*)(VBu + k * 96), A2 + k * A2S + 100 + h0);
    }
  }
  __syncthreads();

  // ---- P4: s2 MFMA (waves 0-1) || v2+vh3 fused (waves 2-3) || zero A1 cols 116..127 ----
  if (wave < 2) {
    int r = lane & 15, q = lane >> 4;
    int nt0 = (wave == 0) ? 0 : 4, nt1 = (wave == 0) ? 4 : 7;
    for (int nt = nt0; nt < nt1; nt++) {
      f32x4v c0 = {0,0,0,0}, c1 = {0,0,0,0};
      int n = nt * 16 + r;
      mfma_nt2<4>(A2, A2S, wsb + B2HI + n * 128, wsb + B2LO + n * 128, lane, c0, c1);
      float base = (n < 100) ? bs2[n] : 0.f;
      unsigned* dst = (unsigned*)A1;
#pragma unroll
      for (int reg = 0; reg < 4; reg++) {
        int m0 = q * 4 + reg, m1 = m0 + 16;
        unsigned hx = f2bf(fmaxf(c0[reg] + base, 0.f));
        unsigned ox = __shfl_down(hx, 1);
        unsigned hy = f2bf(fmaxf(c1[reg] + base, 0.f));
        unsigned oy = __shfl_down(hy, 1);
        if (((lane & 1) == 0) && n < 100) {
          dst[(m0 * A1S + n) >> 1] = hx | (ox << 16);
          if (m1 < 30) dst[(m1 * A1S + n) >> 1] = hy | (oy << 16);
        }
      }
    }
  } else {
    int vt = tid - 128;
    if (vt < 120) {
      int k = vt >> 2, c = vt & 3, h0 = c * 4;
      v_vh_fused<16>((const unsigned*)(VBu + k * 96), Wv2 + h0, Wh3, c, h0,
                     (unsigned*)(VBu + k * 96), A1 + k * A1S + 100 + h0);
    } else {
      // tids 248..255: zero A1 cols 116..127 for s3 (disjoint from MFMA's cols 0..99
      // and the fused task's norm cols 100..115; A1 is not read this phase)
      for (int t = vt - 120; t < 180; t += 8) {
        int r = t / 6, c2 = t % 6;
        ((unsigned*)A1)[r * 84 + 58 + c2] = 0;
      }
    }
  }
  __syncthreads();

  // ---- P6: s3 MFMA with in-epilogue masked K-reduction -> dhs[n] (waves 0-1) || v3 (waves 2-3) ----
  if (wave < 2) {
    unsigned mkb = *(unsigned*)(pool + P_MKB);   // bits 30,31 are 0 -> garbage rows self-excluded
    int r = lane & 15, q = lane >> 4;
    int nt0 = (wave == 0) ? 0 : 4, nt1 = (wave == 0) ? 4 : 7;
    for (int nt = nt0; nt < nt1; nt++) {
      f32x4v c0 = {0,0,0,0}, c1 = {0,0,0,0};
      int n = nt * 16 + r;
      mfma_nt2<4>(A1, A1S, wsb + B3HI + n * 128, wsb + B3LO + n * 128, lane, c0, c1);
      float part = 0.f;
#pragma unroll
      for (int reg = 0; reg < 4; reg++) {
        int m0 = q * 4 + reg, m1 = m0 + 16;
        part += ((mkb >> m0) & 1) ? c0[reg] : 0.f;
        part += ((mkb >> m1) & 1) ? c1[reg] : 0.f;
      }
      part += __shfl_xor(part, 16);   // sum across q-groups (lanes r, r+16, r+32, r+48)
      part += __shfl_xor(part, 32);
      if (q == 0 && n < 100) dhs[n] = part;   // = sum_k mask_k * c[k][n]
    }
  } else {
    int vt = tid - 128;
    if (vt < 120) { int k = vt >> 2, o0 = (vt & 3) * 4;
      vtaskb<16, false>((const unsigned*)(VBu + k * 96), Wv3 + o0, 16, VAp + k*49 + 3*o0); }
  }
  __syncthreads();

  // ---- node phase scratch aliases A1 region (dead after P6; 2032 fl <= 2520) ----
  float* ns   = pool + P_A;
  float* xb   = ns;          // 148
  float* hb   = ns + 160;    // 148
  float* nvh4 = ns + 320;    // 96
  float* nvn4 = ns + 416;    // 32
  float* s4   = ns + 448;    // 400 (+32 vn5 at 848 -> contiguous 432)
  float* nvn5 = ns + 848;    // 32
  float* v4   = ns + 880;    // 96
  float* nvh5 = ns + 976;    // 96
  float* v5   = ns + 1072;   // 48
  float* s5   = ns + 1120;   // 100
  float* red  = ns + 1220;   // 4
  float* part = ns + 1232;   // 800  (ends 2032)

  // ---- P7: masked mean over K -> xb = sv + dh ----
  {
    unsigned mkb = *(unsigned*)(pool + P_MKB);
    float cntf = (float)__popc(mkb);
    for (int f = tid; f < F; f += 256) {
      float acc;
      if (f < 48) { acc = 0.f; for (int k = 0; k < KK; k++) if ((mkb >> k) & 1) acc += VAp[k*49 + f]; }
      else        { int j = f - 48; acc = dhs[j] + cntf * bs3[j]; }
      xb[f] = sv[f] + acc * (1.f / (float)KK);
    }
  }
  __syncthreads();
  // ln0 stats via wave shuffles
  if (tid < 64) {
    float a = (tid < 50) ? xb[48 + 2 * tid] : 0.f;
    float b = (tid < 50) ? xb[48 + 2 * tid + 1] : 0.f;
    float s = a + b, qq = a * a + b * b;
    for (int off = 32; off; off >>= 1) { s += __shfl_down(s, off); qq += __shfl_down(qq, off); }
    if (tid == 0) { red[1] = s * 0.01f; red[2] = qq * 0.01f; }
  } else if (tid < 128) {
    int l = tid - 64;
    float v = (l < 48) ? xb[l] : 0.f;
    float qq = v * v;
    for (int off = 32; off; off >>= 1) qq += __shfl_down(qq, off);
    if (l == 0) red[0] = sqrtf(qq * (1.f / 16.f) + 1e-8f);
  }
  __syncthreads();
  {
    float denom = red[0], mu = red[1];
    float var = red[2] - mu * mu;
    float rs = rsqrtf(var + 1e-5f);
    for (int f = tid; f < F; f += 256) {
      if (f < 48) hb[f] = xb[f] / denom;
      else { int j = f - 48; hb[f] = (xb[f] - mu) * rs * ln0_g[j] + ln0_b[j]; }
    }
  }
  __syncthreads();

  // GVP4: vh4 (16 -> 32), 32 threads, 1 h each
  if (tid < 32) {
    int h = tid;
    float a0 = 0.f, a1 = 0.f, a2 = 0.f;
#pragma unroll 4
    for (int i = 0; i < 16; i++) {
      float w = Wh4[i * 32 + h];
      a0 = fmaf(hb[3*i], w, a0); a1 = fmaf(hb[3*i+1], w, a1); a2 = fmaf(hb[3*i+2], w, a2);
    }
    nvh4[3*h] = a0; nvh4[3*h+1] = a1; nvh4[3*h+2] = a2;
    nvn4[h] = sqrtf(a0*a0 + a1*a1 + a2*a2 + 1e-8f);
  }
  __syncthreads();
  // s_out4 (400 outs, dot 132, relu; 200 threads x 2 cols) || v4 (32 threads, wave 3)
  if (tid < 200) {
    int j0 = tid * 2;
    float ax = bs4[j0], ay = bs4[j0 + 1];
    const float* w = Ws4 + j0;
#pragma unroll 10
    for (int i = 0; i < 100; i++) {
      float s = hb[48 + i];
      float2 w2 = *(const float2*)(w + i * 400);
      ax = fmaf(s, w2.x, ax); ay = fmaf(s, w2.y, ay);
    }
#pragma unroll 8
    for (int h = 0; h < 32; h++) {
      float s = nvn4[h];
      float2 w2 = *(const float2*)(w + (100 + h) * 400);
      ax = fmaf(s, w2.x, ax); ay = fmaf(s, w2.y, ay);
    }
    s4[j0] = fmaxf(ax, 0.f); s4[j0 + 1] = fmaxf(ay, 0.f);
  } else if (tid >= 224) {
    int o = tid - 224;
    float a0 = 0.f, a1 = 0.f, a2 = 0.f;
#pragma unroll 4
    for (int h = 0; h < 32; h++) {
      float w = Wv4[h * 32 + o];
      a0 = fmaf(nvh4[3*h], w, a0); a1 = fmaf(nvh4[3*h+1], w, a1); a2 = fmaf(nvh4[3*h+2], w, a2);
    }
    GATE3(a0, a1, a2, v4[3*o], v4[3*o+1], v4[3*o+2])
  }
  __syncthreads();
  // GVP5: vh5 (32 -> 32), 32 threads
  if (tid < 32) {
    int h = tid;
    float a0 = 0.f, a1 = 0.f, a2 = 0.f;
#pragma unroll 4
    for (int i = 0; i < 32; i++) {
      float w = Wh5[i * 32 + h];
      a0 = fmaf(v4[3*i], w, a0); a1 = fmaf(v4[3*i+1], w, a1); a2 = fmaf(v4[3*i+2], w, a2);
    }
    nvh5[3*h] = a0; nvh5[3*h+1] = a1; nvh5[3*h+2] = a2;
    nvn5[h] = sqrtf(a0*a0 + a1*a1 + a2*a2 + 1e-8f);
  }
  __syncthreads();
  // s_out5 partials (dot 432 split 8 ways, 200 threads) || v5 (16 threads, wave 3)
  if (tid < 200) {
    int jq = tid / 8, c = tid % 8, j0 = jq * 4;
    int ibeg = c * 54, iend = ibeg + 54;
    float4 acc = make_float4(0.f, 0.f, 0.f, 0.f);
    const float* w = Ws5 + j0;
#pragma unroll 6
    for (int i = ibeg; i < iend; i++) {
      float s = s4[i];  // s4[0..399] then nvn5[0..31], contiguous
      float4 w4 = *(const float4*)(w + i * 100);
      acc.x = fmaf(s, w4.x, acc.x); acc.y = fmaf(s, w4.y, acc.y);
      acc.z = fmaf(s, w4.z, acc.z); acc.w = fmaf(s, w4.w, acc.w);
    }
    *(float4*)&part[tid * 4] = acc;
  } else if (tid >= 224 && tid < 240) {
    int o = tid - 224;
    float a0 = 0.f, a1 = 0.f, a2 = 0.f;
#pragma unroll 4
    for (int h = 0; h < 32; h++) {
      float w = Wv5[h * 16 + o];
      a0 = fmaf(nvh5[3*h], w, a0); a1 = fmaf(nvh5[3*h+1], w, a1); a2 = fmaf(nvh5[3*h+2], w, a2);
    }
    v5[3*o] = a0; v5[3*o+1] = a1; v5[3*o+2] = a2;
  }
  __syncthreads();
  if (tid < 25) {
    int j0 = tid * 4;
    float4 b = *(const float4*)(bs5 + j0);
    float4 acc = b;
#pragma unroll
    for (int c = 0; c < 8; c++) {
      float4 p = *(const float4*)&part[(tid * 8 + c) * 4];
      acc.x += p.x; acc.y += p.y; acc.z += p.z; acc.w += p.w;
    }
    *(float4*)&s5[j0] = acc;
  }
  __syncthreads();
  // x2 = h + dh2
  for (int f = tid; f < F; f += 256) {
    float d = (f < 48) ? v5[f] : s5[f - 48];
    xb[f] = hb[f] + d;
  }
  __syncthreads();
  // ln1 stats
  if (tid < 64) {
    float a = (tid < 50) ? xb[48 + 2 * tid] : 0.f;
    float b = (tid < 50) ? xb[48 + 2 * tid + 1] : 0.f;
    float s = a + b, qq = a * a + b * b;
    for (int off = 32; off; off >>= 1) { s += __shfl_down(s, off); qq += __shfl_down(qq, off); }
    if (tid == 0) { red[1] = s * 0.01f; red[2] = qq * 0.01f; }
  } else if (tid < 128) {
    int l = tid - 64;
    float v = (l < 48) ? xb[l] : 0.f;
    float qq = v * v;
    for (int off = 32; off; off >>= 1) qq += __shfl_down(qq, off);
    if (l == 0) red[0] = sqrtf(qq * (1.f / 16.f) + 1e-8f);
  }
  __syncthreads();
  {
    float denom = red[0], mu = red[1];
    float var = red[2] - mu * mu;
    float rs = rsqrtf(var + 1e-5f);
    float mv = (float)mask_V[node];
    for (int f = tid; f < F; f += 256) {
      float val;
      if (f < 48) val = xb[f] / denom;
      else { int j = f - 48; val = (xb[f] - mu) * rs * ln1_g[j] + ln1_b[j]; }
      out[(long)node * F + f] = mv * val;
    }
  }
}

extern "C" void kernel_launch(void* const* d_in, const int* in_sizes, int n_in,
                              void* d_out, int out_size, void* d_ws, size_t ws_size,
                              hipStream_t stream) {
  const float* h_V  = (const float*)d_in[0];
  const float* h_M  = (const float*)d_in[1];
  const int* mask_V = (const int*)d_in[2];
  const int* mask_attend = (const int*)d_in[3];
  const float* Wh1 = (const float*)d_in[4];
  const float* Wv1 = (const float*)d_in[5];
  const float* Ws1 = (const float*)d_in[6];
  const float* bs1 = (const float*)d_in[7];
  const float* Wh2 = (const float*)d_in[8];
  const float* Wv2 = (const float*)d_in[9];
  const float* Ws2 = (const float*)d_in[10];
  const float* bs2 = (const float*)d_in[11];
  const float* Wh3 = (const float*)d_in[12];
  const float* Wv3 = (const float*)d_in[13];
  const float* Ws3 = (const float*)d_in[14];
  const float* bs3 = (const float*)d_in[15];
  const float* Wh4 = (const float*)d_in[16];
  const float* Wv4 = (const float*)d_in[17];
  const float* Ws4 = (const float*)d_in[18];
  const float* bs4 = (const float*)d_in[19];
  const float* Wh5 = (const float*)d_in[20];
  const float* Wv5 = (const float*)d_in[21];
  const float* Ws5 = (const float*)d_in[22];
  const float* bs5 = (const float*)d_in[23];
  const float* ln0_g = (const float*)d_in[24];
  const float* ln0_b = (const float*)d_in[25];
  const float* ln1_g = (const float*)d_in[26];
  const float* ln1_b = (const float*)d_in[27];
  float* out = (float*)d_out;

  float* wsf = (float*)d_ws;
  float* s1bg = wsf + WS_S1B;
  float* vhbg = wsf + WS_VHB;
  ushort* wsb = (ushort*)(wsf + WS_WSB);

  prep_weights<<<dim3(182), dim3(256), 0, stream>>>(Ws1, Ws2, Ws3, wsb);
  prep_node<<<dim3(NNODE / NPB), dim3(256), 0, stream>>>(h_V, Ws1, bs1, Wh1, s1bg, vhbg);
  mpnn_fused<<<dim3(NNODE), dim3(256), 0, stream>>>(
      h_V, h_M, mask_V, mask_attend,
      Wh1, Wv1, Wv2, bs2, Wv3, bs3, Wh2, Wh3,
      Wh4, Wv4, Ws4, bs4, Wh5, Wv5, Ws5, bs5,
      ln0_g, ln0_b, ln1_g, ln1_b, s1bg, vhbg, wsb, out);
}

// Round 4
// 1118.594 us; speedup vs baseline: 1.2289x; 1.1867x over previous
//
#include <hip/hip_runtime.h>

#define KK 30
#define F 148
#define NNODE 16384
#define NPB 16   // nodes per prep_node block
#define NPB2 8   // nodes per node_tail block

typedef short bf16x8 __attribute__((ext_vector_type(8)));
typedef float f32x4v __attribute__((ext_vector_type(4)));

// ---- bf16 helpers (RNE) ----
__device__ __forceinline__ ushort f2bf(float x) {
  unsigned u = __float_as_uint(x);
  unsigned r = (u + 0x7FFF + ((u >> 16) & 1)) >> 16;
  return (ushort)r;
}
__device__ __forceinline__ float bf2f(ushort b) { return __uint_as_float(((unsigned)b) << 16); }
__device__ __forceinline__ unsigned pk2(float x, float y) {
  return (unsigned)f2bf(x) | ((unsigned)f2bf(y) << 16);
}
__device__ __forceinline__ void bsplit(float x, ushort& h, ushort& l) {
  ushort hh = f2bf(x); h = hh; l = f2bf(x - bf2f(hh));
}

// d_ws layout: [ s1bg 16384*100 fl ][ vhbg 16384*96 fl ][ wsb ushorts ]
#define WS_S1B 0
#define WS_VHB (NNODE * 100)
#define WS_WSB (NNODE * 100 + NNODE * 96)
// wsb (ushort offsets): pre-transposed split weights Bt[n][k], hi+lo
#define B1HI 0
#define B1LO 17920   // 112*160
#define B2HI 35840
#define B2LO 50176   // 112*128
#define B3HI 64512
#define B3LO 78848

__global__ void prep_weights(const float* __restrict__ Ws1, const float* __restrict__ Ws2,
                             const float* __restrict__ Ws3, ushort* __restrict__ ws) {
  int i = blockIdx.x * 256 + threadIdx.x;
  if (i < 17920) {                       // B1: [112][160], src rows 100..231 of Ws1 [232][100]
    int n = i / 160, k = i % 160;
    float w = (n < 100 && k < 132) ? Ws1[(100 + k) * 100 + n] : 0.f;
    ushort h, l; bsplit(w, h, l);
    ws[B1HI + i] = h; ws[B1LO + i] = l;
  } else if (i < 17920 + 14336) {        // B2: [112][128], src Ws2 [116][100]
    int j = i - 17920; int n = j / 128, k = j % 128;
    float w = (n < 100 && k < 116) ? Ws2[k * 100 + n] : 0.f;
    ushort h, l; bsplit(w, h, l);
    ws[B2HI + j] = h; ws[B2LO + j] = l;
  } else if (i < 17920 + 2 * 14336) {    // B3: [112][128], src Ws3 [116][100]
    int j = i - 17920 - 14336; int n = j / 128, k = j % 128;
    float w = (n < 100 && k < 116) ? Ws3[k * 100 + n] : 0.f;
    ushort h, l; bsplit(w, h, l);
    ws[B3HI + j] = h; ws[B3LO + j] = l;
  }
}

// per-node k-independent precompute, 16 nodes per block with Ws1^T staged in LDS.
__global__ __launch_bounds__(256)
void prep_node(const float* __restrict__ h_V, const float* __restrict__ Ws1,
               const float* __restrict__ bs1, const float* __restrict__ Wh1,
               float* __restrict__ s1bg, float* __restrict__ vhbg) {
  __shared__ float wt[100 * 101];   // Ws1^T [n][i], pad 101 -> conflict-free column reads
  __shared__ float wh[512];         // Wh1 [16][32]
  __shared__ float svs[NPB * 148];
  const int tid = threadIdx.x;
  const long node0 = (long)blockIdx.x * NPB;
  for (int idx = tid; idx < 10000; idx += 256) {
    int i = idx / 100, n = idx - i * 100;
    wt[n * 101 + i] = Ws1[idx];     // coalesced read, scattered LDS write
  }
  for (int idx = tid; idx < 512; idx += 256) wh[idx] = Wh1[idx];
  for (int idx = tid; idx < NPB * 148; idx += 256) {
    int nd = idx / 148, f = idx - nd * 148;
    svs[idx] = h_V[(node0 + nd) * 148 + f];
  }
  __syncthreads();
  for (int task = tid; task < NPB * 100; task += 256) {
    int nd = task / 100, n = task - nd * 100;
    const float* s = svs + nd * 148 + 48;
    const float* w = wt + n * 101;
    float acc = bs1[n];
#pragma unroll 10
    for (int i = 0; i < 100; i++) acc = fmaf(s[i], w[i], acc);
    s1bg[(node0 + nd) * 100 + n] = acc;
  }
  for (int task = tid; task < NPB * 32; task += 256) {
    int nd = task >> 5, h = task & 31;
    const float* s = svs + nd * 148;
    float a0 = 0.f, a1 = 0.f, a2 = 0.f;
#pragma unroll 4
    for (int i = 0; i < 16; i++) {
      float w = wh[i * 32 + h];
      a0 = fmaf(s[3*i], w, a0); a1 = fmaf(s[3*i+1], w, a1); a2 = fmaf(s[3*i+2], w, a2);
    }
    vhbg[(node0 + nd) * 96 + 3*h + 0] = a0;
    vhbg[(node0 + nd) * 96 + 3*h + 1] = a1;
    vhbg[(node0 + nd) * 96 + 3*h + 2] = a2;
  }
}

#define DECL12 float a00=0,a01=0,a02=0,a10=0,a11=0,a12=0,a20=0,a21=0,a22=0,a30=0,a31=0,a32=0;
#define FMA3x4(v0_,v1_,v2_,w_) \
  a00=fmaf(v0_,w_.x,a00); a01=fmaf(v1_,w_.x,a01); a02=fmaf(v2_,w_.x,a02); \
  a10=fmaf(v0_,w_.y,a10); a11=fmaf(v1_,w_.y,a11); a12=fmaf(v2_,w_.y,a12); \
  a20=fmaf(v0_,w_.z,a20); a21=fmaf(v1_,w_.z,a21); a22=fmaf(v2_,w_.z,a22); \
  a30=fmaf(v0_,w_.w,a30); a31=fmaf(v1_,w_.w,a31); a32=fmaf(v2_,w_.w,a32);

#define GATE3(x0,x1,x2,d0,d1,d2) { float vn_=sqrtf((x0)*(x0)+(x1)*(x1)+(x2)*(x2)+1e-8f); \
  float g_=1.f/(1.f+expf(-vn_)); d0=(x0)*g_; d1=(x1)*g_; d2=(x2)*g_; }

// vector-path matvec, 4 outputs, bf16-packed source (VBu), fp32 dest
template<int NI, bool GATEF>
__device__ __forceinline__ void vtaskb(const unsigned* __restrict__ vsrc,
                                       const float* __restrict__ wbase, int wstride,
                                       float* __restrict__ vdst)
{
  DECL12
#pragma unroll 4
  for (int h2 = 0; h2 < NI / 2; h2++) {
    unsigned d0 = vsrc[3*h2+0], d1 = vsrc[3*h2+1], d2 = vsrc[3*h2+2];
    float4 w0 = *(const float4*)(wbase + (2*h2) * wstride);
    float4 w1 = *(const float4*)(wbase + (2*h2+1) * wstride);
    float e0 = bf2f((ushort)d0), e1 = bf2f((ushort)(d0 >> 16)), e2 = bf2f((ushort)d1);
    float g0 = bf2f((ushort)(d1 >> 16)), g1 = bf2f((ushort)d2), g2 = bf2f((ushort)(d2 >> 16));
    FMA3x4(e0, e1, e2, w0)
    FMA3x4(g0, g1, g2, w1)
  }
  if (GATEF) {
    GATE3(a00,a01,a02, vdst[0],vdst[1],vdst[2])
    GATE3(a10,a11,a12, vdst[3],vdst[4],vdst[5])
    GATE3(a20,a21,a22, vdst[6],vdst[7],vdst[8])
    GATE3(a30,a31,a32, vdst[9],vdst[10],vdst[11])
  } else {
    vdst[0]=a00; vdst[1]=a01; vdst[2]=a02;  vdst[3]=a10; vdst[4]=a11; vdst[5]=a12;
    vdst[6]=a20; vdst[7]=a21; vdst[8]=a22;  vdst[9]=a30; vdst[10]=a31; vdst[11]=a32;
  }
}

// Fused: gated v-task (NI inputs -> 16 outputs, this thread owns o0=c*4..c*4+3)
// + next-stage vh (16 -> 16) via 4-lane xor exchange of the gated values.
// Named scalars only (R2's arrays went to scratch: +200 MB HBM writes).
template<int NI>
__device__ __forceinline__ void v_vh_fused(const unsigned* vsrc,
                                           const float* __restrict__ Wv,   // pre-offset by o0
                                           const float* __restrict__ Whn,  // [16][16]
                                           int c, int h0,
                                           unsigned* vrow_u, ushort* ncol)
{
  DECL12
#pragma unroll
  for (int h2 = 0; h2 < NI / 2; h2++) {
    unsigned d0 = vsrc[3*h2+0], d1 = vsrc[3*h2+1], d2 = vsrc[3*h2+2];
    float4 w0 = *(const float4*)(Wv + (2*h2) * 16);
    float4 w1 = *(const float4*)(Wv + (2*h2+1) * 16);
    float e0 = bf2f((ushort)d0), e1 = bf2f((ushort)(d0 >> 16)), e2 = bf2f((ushort)d1);
    float f0 = bf2f((ushort)(d1 >> 16)), f1 = bf2f((ushort)d2), f2 = bf2f((ushort)(d2 >> 16));
    FMA3x4(e0, e1, e2, w0)
    FMA3x4(f0, f1, f2, w1)
  }
  float g0,g1,g2,g3,g4,g5,g6,g7,g8,g9,g10,g11;
  GATE3(a00,a01,a02, g0,g1,g2)
  GATE3(a10,a11,a12, g3,g4,g5)
  GATE3(a20,a21,a22, g6,g7,g8)
  GATE3(a30,a31,a32, g9,g10,g11)
  a00=0;a01=0;a02=0;a10=0;a11=0;a12=0;a20=0;a21=0;a22=0;a30=0;a31=0;a32=0;
  {   // m = 0: own gated values, weight rows c*4..c*4+3
    int ob = c * 4;
    float4 w;
    w = *(const float4*)(Whn + (ob+0)*16 + h0); FMA3x4(g0,g1,g2,w)
    w = *(const float4*)(Whn + (ob+1)*16 + h0); FMA3x4(g3,g4,g5,w)
    w = *(const float4*)(Whn + (ob+2)*16 + h0); FMA3x4(g6,g7,g8,w)
    w = *(const float4*)(Whn + (ob+3)*16 + h0); FMA3x4(g9,g10,g11,w)
  }
#define XCH_ACC(m_) { \
    float t0=__shfl_xor(g0,m_),  t1=__shfl_xor(g1,m_),  t2=__shfl_xor(g2,m_), \
          t3=__shfl_xor(g3,m_),  t4=__shfl_xor(g4,m_),  t5=__shfl_xor(g5,m_), \
          t6=__shfl_xor(g6,m_),  t7=__shfl_xor(g7,m_),  t8=__shfl_xor(g8,m_), \
          t9=__shfl_xor(g9,m_), t10=__shfl_xor(g10,m_), t11=__shfl_xor(g11,m_); \
    int ob = (c ^ m_) * 4; \
    float4 w; \
    w = *(const float4*)(Whn + (ob+0)*16 + h0); FMA3x4(t0,t1,t2,w) \
    w = *(const float4*)(Whn + (ob+1)*16 + h0); FMA3x4(t3,t4,t5,w) \
    w = *(const float4*)(Whn + (ob+2)*16 + h0); FMA3x4(t6,t7,t8,w) \
    w = *(const float4*)(Whn + (ob+3)*16 + h0); FMA3x4(t9,t10,t11,w) }
  XCH_ACC(1)
  XCH_ACC(2)
  XCH_ACC(3)
#undef XCH_ACC
  unsigned* vb = vrow_u + ((3 * h0) >> 1);
  vb[0]=pk2(a00,a01); vb[1]=pk2(a02,a10); vb[2]=pk2(a11,a12);
  vb[3]=pk2(a20,a21); vb[4]=pk2(a22,a30); vb[5]=pk2(a31,a32);
  float n0 = sqrtf(a00*a00+a01*a01+a02*a02 + 1e-8f);
  float n1 = sqrtf(a10*a10+a11*a11+a12*a12 + 1e-8f);
  float n2 = sqrtf(a20*a20+a21*a21+a22*a22 + 1e-8f);
  float n3 = sqrtf(a30*a30+a31*a31+a32*a32 + 1e-8f);
  unsigned* p = (unsigned*)ncol;
  p[0] = pk2(n0, n1); p[1] = pk2(n2, n3);
}

// 2-term split-bf16 MFMA over one n-tile, two m-tiles. A hi-only from LDS; B hi+lo from L2.
template<int NKS>
__device__ __forceinline__ void mfma_nt2(const ushort* __restrict__ A, int astr,
                                         const ushort* __restrict__ B_hi,
                                         const ushort* __restrict__ B_lo,
                                         int lane, f32x4v& c0, f32x4v& c1)
{
  int r = lane & 15, q = lane >> 4;
  const int ka = q * 8;
#pragma unroll
  for (int ks = 0; ks < NKS; ks++) {
    int ko = ka + ks * 32;
    bf16x8 a0 = *(const bf16x8*)(A + r * astr + ko);
    bf16x8 a1 = *(const bf16x8*)(A + (16 + r) * astr + ko);
    bf16x8 bh = *(const bf16x8*)(B_hi + ko);
    bf16x8 bl = *(const bf16x8*)(B_lo + ko);
    c0 = __builtin_amdgcn_mfma_f32_16x16x32_bf16(a0, bh, c0, 0, 0, 0);
    c0 = __builtin_amdgcn_mfma_f32_16x16x32_bf16(a0, bl, c0, 0, 0, 0);
    c1 = __builtin_amdgcn_mfma_f32_16x16x32_bf16(a1, bh, c1, 0, 0, 0);
    c1 = __builtin_amdgcn_mfma_f32_16x16x32_bf16(a1, bl, c1, 0, 0, 0);
  }
}

// LDS pool carving (float offsets), 30888 B -> 5 blocks/CU.
#define P_SV   0      // sv 148 fl
#define P_MKB  148    // 1 fl (ballot mask)
#define P_DH   152    // dhs [100] -> ends 252
#define P_A2   252    // A2 ushort [30][136] = 2040 fl -> ends 2292
#define P_A    2292   // A1 ushort [30][168] = 2520 fl -> ends 4812
#define P_VA   4812   // VAp [30][49] fp32 -> ends 6282
#define P_VB   6282   // VBu [30][96] bf16 = 1440 fl -> ends 7722
#define A1S 168
#define A2S 136
#define POOL_F 7722   // 30888 B

// Edge kernel: P0..P7 only; node tail moved to node_tail (8 nodes/block, dense).
// Writes xb (pre-ln0 residual input) to xg == out buffer; node_tail reads+overwrites in place.
// Role swap: vwave = wave ^ (hash(node)&2) alternates which SIMDs host the MFMA vs
// VALU-heavy role across blocks (wave i -> SIMD i%4 pinning would otherwise put all
// v-task work on SIMDs 2,3 of every CU).
__global__ __launch_bounds__(256, 5)
void mpnn_edge(const float* __restrict__ h_V, const float* __restrict__ h_M,
               const int* __restrict__ mask_attend,
               const float* __restrict__ Wh1, const float* __restrict__ Wv1,
               const float* __restrict__ Wv2, const float* __restrict__ bs2,
               const float* __restrict__ Wv3, const float* __restrict__ bs3,
               const float* __restrict__ Wh2, const float* __restrict__ Wh3,
               const float* __restrict__ s1bg, const float* __restrict__ vhbg,
               const ushort* __restrict__ wsb,
               float* __restrict__ xg)
{
  __shared__ float pool[POOL_F];
  float* sv   = pool + P_SV;
  float* dhs  = pool + P_DH;                 // [100]
  float* VAp  = pool + P_VA;                 // stride 49 fp32
  ushort* VBu = (ushort*)(pool + P_VB);      // [30][96] packed bf16
  ushort* A1 = (ushort*)(pool + P_A);        // [30][A1S]
  ushort* A2 = (ushort*)(pool + P_A2);       // [30][A2S]

  const int tid = threadIdx.x;
  const int node = blockIdx.x;
  const int wave = tid >> 6, lane = tid & 63;
  const int vwave = wave ^ (int)(((unsigned)node * 0x9E3779B1u >> 16) & 2u);

  // ---- P0: stage node feats + edge feats + zero A K-pads + mask ballot ----
  for (int f = tid; f < F; f += 256) sv[f] = h_V[(long)node * F + f];
  {
    unsigned long long bal = __ballot(tid < KK && mask_attend[node * KK + tid] != 0);
    if (tid == 0) *(unsigned*)(pool + P_MKB) = (unsigned)bal;
  }
  for (int t = tid; t < 420; t += 256) {
    int r = t / 14, c2 = t % 14;
    ((unsigned*)A1)[r * 84 + 66 + c2] = 0;
  }
  for (int t = tid; t < 180; t += 256) {
    int r = t / 6, c2 = t % 6;
    ((unsigned*)A2)[r * 68 + 58 + c2] = 0;
  }
  for (int task = tid; task < KK * 37; task += 256) {
    int k = task / 37, q = task % 37;
    float4 d = *(const float4*)(h_M + ((long)node * KK + k) * F + q * 4);
    if (q < 12) {
      VAp[k * 49 + q * 4 + 0] = d.x; VAp[k * 49 + q * 4 + 1] = d.y;
      VAp[k * 49 + q * 4 + 2] = d.z; VAp[k * 49 + q * 4 + 3] = d.w;
    } else {
      int j0 = q * 4 - 48;
      unsigned* p = (unsigned*)(A1 + k * A1S + j0);
      p[0] = (unsigned)f2bf(d.x) | ((unsigned)f2bf(d.y) << 16);
      p[1] = (unsigned)f2bf(d.z) | ((unsigned)f2bf(d.w) << 16);
    }
  }
  __syncthreads();

  // ---- P1: vh1 (240 threads, 4h each; node-half from vhbg) ----
  if (tid < 240) {
    int k = tid >> 3, h0 = (tid & 7) * 4;
    const float4* vb4 = (const float4*)(vhbg + (long)node * 96 + 3 * h0);
    float4 q0 = vb4[0], q1 = vb4[1], q2 = vb4[2];
    float a00=q0.x,a01=q0.y,a02=q0.z, a10=q0.w,a11=q1.x,a12=q1.y,
          a20=q1.z,a21=q1.w,a22=q2.x, a30=q2.y,a31=q2.z,a32=q2.w;
#pragma unroll 4
    for (int i = 0; i < 16; i++) {            // vM rows
      float v0 = VAp[k*49+3*i], v1 = VAp[k*49+3*i+1], v2 = VAp[k*49+3*i+2];
      float4 w = *(const float4*)(Wh1 + (16 + i) * 32 + h0);
      FMA3x4(v0, v1, v2, w)
    }
    unsigned* vb = (unsigned*)(VBu + k * 96 + 3 * h0);
    vb[0]=pk2(a00,a01); vb[1]=pk2(a02,a10); vb[2]=pk2(a11,a12);
    vb[3]=pk2(a20,a21); vb[4]=pk2(a22,a30); vb[5]=pk2(a31,a32);
    float n0 = sqrtf(a00*a00+a01*a01+a02*a02 + 1e-8f);
    float n1 = sqrtf(a10*a10+a11*a11+a12*a12 + 1e-8f);
    float n2 = sqrtf(a20*a20+a21*a21+a22*a22 + 1e-8f);
    float n3 = sqrtf(a30*a30+a31*a31+a32*a32 + 1e-8f);
    unsigned* p = (unsigned*)(A1 + k * A1S + 100 + h0);  // vn1 cols 100..131
    p[0] = pk2(n0, n1); p[1] = pk2(n2, n3);
  }
  __syncthreads();

  // ---- P2: s1 MFMA (vwave 0-1) || v1+vh2 fused (vwave 2-3) ----
  if (vwave < 2) {
    int r = lane & 15, q = lane >> 4;
    int nt0 = (vwave == 0) ? 0 : 4, nt1 = (vwave == 0) ? 4 : 7;
    for (int nt = nt0; nt < nt1; nt++) {
      int n = nt * 16 + r;
      float base = (n < 100) ? s1bg[(long)node * 100 + n] : 0.f;
      f32x4v c0 = {0,0,0,0}, c1 = {0,0,0,0};
      mfma_nt2<5>(A1, A1S, wsb + B1HI + n * 160, wsb + B1LO + n * 160, lane, c0, c1);
      unsigned* dst = (unsigned*)A2;
#pragma unroll
      for (int reg = 0; reg < 4; reg++) {
        int m0 = q * 4 + reg, m1 = m0 + 16;
        unsigned hx = f2bf(fmaxf(c0[reg] + base, 0.f));
        unsigned ox = __shfl_down(hx, 1);
        unsigned hy = f2bf(fmaxf(c1[reg] + base, 0.f));
        unsigned oy = __shfl_down(hy, 1);
        if (((lane & 1) == 0) && n < 100) {
          dst[(m0 * A2S + n) >> 1] = hx | (ox << 16);
          if (m1 < 30) dst[(m1 * A2S + n) >> 1] = hy | (oy << 16);
        }
      }
    }
  } else {
    int vt = ((vwave - 2) << 6) + lane;
    if (vt < 120) {
      int k = vt >> 2, c = vt & 3, h0 = c * 4;
      v_vh_fused<32>((const unsigned*)(VBu + k * 96), Wv1 + h0, Wh2, c, h0,
                     (unsigned*)(VBu + k * 96), A2 + k * A2S + 100 + h0);
    }
  }
  __syncthreads();

  // ---- P4: s2 MFMA || v2+vh3 fused || zero A1 cols 116..127 ----
  if (vwave < 2) {
    int r = lane & 15, q = lane >> 4;
    int nt0 = (vwave == 0) ? 0 : 4, nt1 = (vwave == 0) ? 4 : 7;
    for (int nt = nt0; nt < nt1; nt++) {
      f32x4v c0 = {0,0,0,0}, c1 = {0,0,0,0};
      int n = nt * 16 + r;
      mfma_nt2<4>(A2, A2S, wsb + B2HI + n * 128, wsb + B2LO + n * 128, lane, c0, c1);
      float base = (n < 100) ? bs2[n] : 0.f;
      unsigned* dst = (unsigned*)A1;
#pragma unroll
      for (int reg = 0; reg < 4; reg++) {
        int m0 = q * 4 + reg, m1 = m0 + 16;
        unsigned hx = f2bf(fmaxf(c0[reg] + base, 0.f));
        unsigned ox = __shfl_down(hx, 1);
        unsigned hy = f2bf(fmaxf(c1[reg] + base, 0.f));
        unsigned oy = __shfl_down(hy, 1);
        if (((lane & 1) == 0) && n < 100) {
          dst[(m0 * A1S + n) >> 1] = hx | (ox << 16);
          if (m1 < 30) dst[(m1 * A1S + n) >> 1] = hy | (oy << 16);
        }
      }
    }
  } else {
    int vt = ((vwave - 2) << 6) + lane;
    if (vt < 120) {
      int k = vt >> 2, c = vt & 3, h0 = c * 4;
      v_vh_fused<16>((const unsigned*)(VBu + k * 96), Wv2 + h0, Wh3, c, h0,
                     (unsigned*)(VBu + k * 96), A1 + k * A1S + 100 + h0);
    } else {
      // 8 threads: zero A1 cols 116..127 for s3
      for (int t = vt - 120; t < 180; t += 8) {
        int r = t / 6, c2 = t % 6;
        ((unsigned*)A1)[r * 84 + 58 + c2] = 0;
      }
    }
  }
  __syncthreads();

  // ---- P6: s3 MFMA + in-epilogue masked K-reduction -> dhs || v3 ----
  if (vwave < 2) {
    unsigned mkb = *(unsigned*)(pool + P_MKB);
    int r = lane & 15, q = lane >> 4;
    int nt0 = (vwave == 0) ? 0 : 4, nt1 = (vwave == 0) ? 4 : 7;
    for (int nt = nt0; nt < nt1; nt++) {
      f32x4v c0 = {0,0,0,0}, c1 = {0,0,0,0};
      int n = nt * 16 + r;
      mfma_nt2<4>(A1, A1S, wsb + B3HI + n * 128, wsb + B3LO + n * 128, lane, c0, c1);
      float part = 0.f;
#pragma unroll
      for (int reg = 0; reg < 4; reg++) {
        int m0 = q * 4 + reg, m1 = m0 + 16;
        part += ((mkb >> m0) & 1) ? c0[reg] : 0.f;
        part += ((mkb >> m1) & 1) ? c1[reg] : 0.f;
      }
      part += __shfl_xor(part, 16);
      part += __shfl_xor(part, 32);
      if (q == 0 && n < 100) dhs[n] = part;
    }
  } else {
    int vt = ((vwave - 2) << 6) + lane;
    if (vt < 120) { int k = vt >> 2, o0 = (vt & 3) * 4;
      vtaskb<16, false>((const unsigned*)(VBu + k * 96), Wv3 + o0, 16, VAp + k*49 + 3*o0); }
  }
  __syncthreads();

  // ---- P7: masked mean over K -> xg = sv + dh (global; node_tail consumes) ----
  {
    unsigned mkb = *(unsigned*)(pool + P_MKB);
    float cntf = (float)__popc(mkb);
    for (int f = tid; f < F; f += 256) {
      float acc;
      if (f < 48) { acc = 0.f; for (int k = 0; k < KK; k++) if ((mkb >> k) & 1) acc += VAp[k*49 + f]; }
      else        { int j = f - 48; acc = dhs[j] + cntf * bs3[j]; }
      xg[(long)node * F + f] = sv[f] + acc * (1.f / (float)KK);
    }
  }
}

// Node tail: 8 nodes/block, all phases dense, barriers amortized 8x.
// Reads xb from xg (== out) and overwrites the same rows in place.
__global__ __launch_bounds__(256, 4)
void node_tail(const float* __restrict__ xg, const int* __restrict__ mask_V,
               const float* __restrict__ Wh4, const float* __restrict__ Wv4,
               const float* __restrict__ Ws4, const float* __restrict__ bs4,
               const float* __restrict__ Wh5, const float* __restrict__ Wv5,
               const float* __restrict__ Ws5, const float* __restrict__ bs5,
               const float* __restrict__ ln0_g, const float* __restrict__ ln0_b,
               const float* __restrict__ ln1_g, const float* __restrict__ ln1_b,
               float* __restrict__ out)
{
  __shared__ float xbs[NPB2][148];
  __shared__ float hb[NPB2][160];
  __shared__ float nvh4[NPB2][96];
  __shared__ float nvn4[NPB2][32];
  __shared__ float s4s[NPB2][432];   // s4[0..399] + vn5[400..431], contiguous for s5 dot
  __shared__ float v4s[NPB2][96];
  __shared__ float nvh5[NPB2][96];
  __shared__ float v5s[NPB2][48];
  __shared__ float s5s[NPB2][100];
  __shared__ float red[NPB2][4];
  const int tid = threadIdx.x;
  const long node0 = (long)blockIdx.x * NPB2;

  // stage
  for (int idx = tid; idx < NPB2 * 148; idx += 256) {
    int nd = idx / 148, f = idx - nd * 148;
    xbs[nd][f] = xg[(node0 + nd) * 148 + f];
  }
  __syncthreads();
  // ln0 stats: one 32-lane group per node (xor-shuffles stay in-group for off<32)
  {
    int nd = tid >> 5, l = tid & 31;
    float a = 0.f, qq = 0.f, vq = 0.f;
    for (int j = l; j < 100; j += 32) { float x = xbs[nd][48 + j]; a += x; qq = fmaf(x, x, qq); }
    for (int j = l; j < 48; j += 32)  { float x = xbs[nd][j]; vq = fmaf(x, x, vq); }
#pragma unroll
    for (int off = 16; off; off >>= 1) {
      a += __shfl_xor(a, off); qq += __shfl_xor(qq, off); vq += __shfl_xor(vq, off);
    }
    if (l == 0) {
      red[nd][0] = sqrtf(vq * (1.f / 16.f) + 1e-8f);
      red[nd][1] = a * 0.01f; red[nd][2] = qq * 0.01f;
    }
  }
  __syncthreads();
  for (int idx = tid; idx < NPB2 * 148; idx += 256) {
    int nd = idx / 148, f = idx - nd * 148;
    float denom = red[nd][0], mu = red[nd][1];
    float rs = rsqrtf(red[nd][2] - mu * mu + 1e-5f);
    hb[nd][f] = (f < 48) ? xbs[nd][f] / denom
                         : (xbs[nd][f] - mu) * rs * ln0_g[f - 48] + ln0_b[f - 48];
  }
  __syncthreads();
  // vh4: 8 nodes x 32 h = 256 tasks
  {
    int nd = tid >> 5, h = tid & 31;
    float a0 = 0.f, a1 = 0.f, a2 = 0.f;
#pragma unroll 4
    for (int i = 0; i < 16; i++) {
      float w = Wh4[i * 32 + h];
      a0 = fmaf(hb[nd][3*i], w, a0); a1 = fmaf(hb[nd][3*i+1], w, a1); a2 = fmaf(hb[nd][3*i+2], w, a2);
    }
    nvh4[nd][3*h] = a0; nvh4[nd][3*h+1] = a1; nvh4[nd][3*h+2] = a2;
    nvn4[nd][h] = sqrtf(a0*a0 + a1*a1 + a2*a2 + 1e-8f);
  }
  __syncthreads();
  // s4 (800 float4-col tasks) then v4 (256 tasks), independent
  for (int task = tid; task < NPB2 * 100; task += 256) {
    int nd = task / 100, jq = task - nd * 100, j0 = jq * 4;
    float4 acc = *(const float4*)(bs4 + j0);
    const float* w = Ws4 + j0;
#pragma unroll 10
    for (int i = 0; i < 100; i++) {
      float s = hb[nd][48 + i];
      float4 w4 = *(const float4*)(w + i * 400);
      acc.x = fmaf(s, w4.x, acc.x); acc.y = fmaf(s, w4.y, acc.y);
      acc.z = fmaf(s, w4.z, acc.z); acc.w = fmaf(s, w4.w, acc.w);
    }
#pragma unroll 8
    for (int h = 0; h < 32; h++) {
      float s = nvn4[nd][h];
      float4 w4 = *(const float4*)(w + (100 + h) * 400);
      acc.x = fmaf(s, w4.x, acc.x); acc.y = fmaf(s, w4.y, acc.y);
      acc.z = fmaf(s, w4.z, acc.z); acc.w = fmaf(s, w4.w, acc.w);
    }
    acc.x = fmaxf(acc.x, 0.f); acc.y = fmaxf(acc.y, 0.f);
    acc.z = fmaxf(acc.z, 0.f); acc.w = fmaxf(acc.w, 0.f);
    *(float4*)&s4s[nd][j0] = acc;
  }
  {
    int nd = tid >> 5, o = tid & 31;
    float a0 = 0.f, a1 = 0.f, a2 = 0.f;
#pragma unroll 8
    for (int h = 0; h < 32; h++) {
      float w = Wv4[h * 32 + o];
      a0 = fmaf(nvh4[nd][3*h], w, a0); a1 = fmaf(nvh4[nd][3*h+1], w, a1); a2 = fmaf(nvh4[nd][3*h+2], w, a2);
    }
    GATE3(a0, a1, a2, v4s[nd][3*o], v4s[nd][3*o+1], v4s[nd][3*o+2])
  }
  __syncthreads();
  // vh5: 256 tasks; norms into s4s[][400..431]
  {
    int nd = tid >> 5, h = tid & 31;
    float a0 = 0.f, a1 = 0.f, a2 = 0.f;
#pragma unroll 8
    for (int i = 0; i < 32; i++) {
      float w = Wh5[i * 32 + h];
      a0 = fmaf(v4s[nd][3*i], w, a0); a1 = fmaf(v4s[nd][3*i+1], w, a1); a2 = fmaf(v4s[nd][3*i+2], w, a2);
    }
    nvh5[nd][3*h] = a0; nvh5[nd][3*h+1] = a1; nvh5[nd][3*h+2] = a2;
    s4s[nd][400 + h] = sqrtf(a0*a0 + a1*a1 + a2*a2 + 1e-8f);
  }
  __syncthreads();
  // s5 (200 float4-col tasks, full dot-432) || v5 (32 threads x 4 tasks)
  if (tid < NPB2 * 25) {
    int nd = tid / 25, jq = tid - nd * 25, j0 = jq * 4;
    float4 acc = *(const float4*)(bs5 + j0);
    const float* w = Ws5 + j0;
#pragma unroll 8
    for (int i = 0; i < 432; i++) {
      float s = s4s[nd][i];
      float4 w4 = *(const float4*)(w + i * 100);
      acc.x = fmaf(s, w4.x, acc.x); acc.y = fmaf(s, w4.y, acc.y);
      acc.z = fmaf(s, w4.z, acc.z); acc.w = fmaf(s, w4.w, acc.w);
    }
    *(float4*)&s5s[nd][j0] = acc;
  } else if (tid >= 224) {
    for (int t = tid - 224; t < NPB2 * 16; t += 32) {
      int nd = t >> 4, o = t & 15;
      float a0 = 0.f, a1 = 0.f, a2 = 0.f;
#pragma unroll 8
      for (int h = 0; h < 32; h++) {
        float w = Wv5[h * 16 + o];
        a0 = fmaf(nvh5[nd][3*h], w, a0); a1 = fmaf(nvh5[nd][3*h+1], w, a1); a2 = fmaf(nvh5[nd][3*h+2], w, a2);
      }
      v5s[nd][3*o] = a0; v5s[nd][3*o+1] = a1; v5s[nd][3*o+2] = a2;
    }
  }
  __syncthreads();
  // x2 = hb + dh2 (into xbs)
  for (int idx = tid; idx < NPB2 * 148; idx += 256) {
    int nd = idx / 148, f = idx - nd * 148;
    float d = (f < 48) ? v5s[nd][f] : s5s[nd][f - 48];
    xbs[nd][f] = hb[nd][f] + d;
  }
  __syncthreads();
  // ln1 stats
  {
    int nd = tid >> 5, l = tid & 31;
    float a = 0.f, qq = 0.f, vq = 0.f;
    for (int j = l; j < 100; j += 32) { float x = xbs[nd][48 + j]; a += x; qq = fmaf(x, x, qq); }
    for (int j = l; j < 48; j += 32)  { float x = xbs[nd][j]; vq = fmaf(x, x, vq); }
#pragma unroll
    for (int off = 16; off; off >>= 1) {
      a += __shfl_xor(a, off); qq += __shfl_xor(qq, off); vq += __shfl_xor(vq, off);
    }
    if (l == 0) {
      red[nd][0] = sqrtf(vq * (1.f / 16.f) + 1e-8f);
      red[nd][1] = a * 0.01f; red[nd][2] = qq * 0.01f;
    }
  }
  __syncthreads();
  for (int idx = tid; idx < NPB2 * 148; idx += 256) {
    int nd = idx / 148, f = idx - nd * 148;
    float denom = red[nd][0], mu = red[nd][1];
    float rs = rsqrtf(red[nd][2] - mu * mu + 1e-5f);
    float mv = (float)mask_V[node0 + nd];
    float val = (f < 48) ? xbs[nd][f] / denom
                         : (xbs[nd][f] - mu) * rs * ln1_g[f - 48] + ln1_b[f - 48];
    out[(node0 + nd) * 148 + f] = mv * val;
  }
}

extern "C" void kernel_launch(void* const* d_in, const int* in_sizes, int n_in,
                              void* d_out, int out_size, void* d_ws, size_t ws_size,
                              hipStream_t stream) {
  const float* h_V  = (const float*)d_in[0];
  const float* h_M  = (const float*)d_in[1];
  const int* mask_V = (const int*)d_in[2];
  const int* mask_attend = (const int*)d_in[3];
  const float* Wh1 = (const float*)d_in[4];
  const float* Wv1 = (const float*)d_in[5];
  const float* Ws1 = (const float*)d_in[6];
  const float* bs1 = (const float*)d_in[7];
  const float* Wh2 = (const float*)d_in[8];
  const float* Wv2 = (const float*)d_in[9];
  const float* Ws2 = (const float*)d_in[10];
  const float* bs2 = (const float*)d_in[11];
  const float* Wh3 = (const float*)d_in[12];
  const float* Wv3 = (const float*)d_in[13];
  const float* Ws3 = (const float*)d_in[14];
  const float* bs3 = (const float*)d_in[15];
  const float* Wh4 = (const float*)d_in[16];
  const float* Wv4 = (const float*)d_in[17];
  const float* Ws4 = (const float*)d_in[18];
  const float* bs4 = (const float*)d_in[19];
  const float* Wh5 = (const float*)d_in[20];
  const float* Wv5 = (const float*)d_in[21];
  const float* Ws5 = (const float*)d_in[22];
  const float* bs5 = (const float*)d_in[23];
  const float* ln0_g = (const float*)d_in[24];
  const float* ln0_b = (const float*)d_in[25];
  const float* ln1_g = (const float*)d_in[26];
  const float* ln1_b = (const float*)d_in[27];
  float* out = (float*)d_out;

  float* wsf = (float*)d_ws;
  float* s1bg = wsf + WS_S1B;
  float* vhbg = wsf + WS_VHB;
  ushort* wsb = (ushort*)(wsf + WS_WSB);

  prep_weights<<<dim3(182), dim3(256), 0, stream>>>(Ws1, Ws2, Ws3, wsb);
  prep_node<<<dim3(NNODE / NPB), dim3(256), 0, stream>>>(h_V, Ws1, bs1, Wh1, s1bg, vhbg);
  mpnn_edge<<<dim3(NNODE), dim3(256), 0, stream>>>(
      h_V, h_M, mask_attend,
      Wh1, Wv1, Wv2, bs2, Wv3, bs3, Wh2, Wh3,
      s1bg, vhbg, wsb, out);
  node_tail<<<dim3(NNODE / NPB2), dim3(256), 0, stream>>>(
      out, mask_V, Wh4, Wv4, Ws4, bs4, Wh5, Wv5, Ws5, bs5,
      ln0_g, ln0_b, ln1_g, ln1_b, out);
}